// Round 2
// baseline (1590.539 us; speedup 1.0000x reference)
//
#include <hip/hip_runtime.h>
#include <hip/hip_bf16.h>

#define BQ 4
#define LQ 4096
#define HID 1024
#define NHEAD 8
#define DHEAD 128
#define MROWS (BQ * LQ) /* 16384 */

typedef __bf16 bf16x8 __attribute__((ext_vector_type(8)));
typedef float f32x4 __attribute__((ext_vector_type(4)));

__device__ __forceinline__ float bf2f(unsigned short u) {
    return __uint_as_float(((unsigned int)u) << 16);
}
__device__ __forceinline__ unsigned short f2us(float f) {
    __hip_bfloat16 b = __float2bfloat16(f);
    return *reinterpret_cast<unsigned short*>(&b);
}
// Read element i of p as float, where p is f32 (isf) or bf16 (!isf).
__device__ __forceinline__ float loadAny(const void* p, size_t i, bool isf) {
    return isf ? ((const float*)p)[i] : bf2f(((const unsigned short*)p)[i]);
}

// ---------------------------------------------------------------------------
// Dtype probe: x ~ N(0,1). If x is f32, even-index uint16s are low mantissa
// halves -> exponent-field uniform random -> ~89% "anomalous". If x is bf16,
// even-index values are genuine N(0,1) bf16 -> ~0% anomalous.
// flag = 1 -> inputs are f32; flag = 0 -> inputs are bf16.
// ---------------------------------------------------------------------------
__global__ void detect_kernel(const void* x, int* flag) {
    const unsigned short* u = (const unsigned short*)x;
    int t = threadIdx.x;  // 64 threads
    int cnt = 0;
#pragma unroll
    for (int s = 0; s < 64; ++s) {
        unsigned short v = u[2 * (t * 64 + s)];
        int e = (v >> 7) & 0xFF;
        cnt += (e >= 0x8A || (e != 0 && e <= 0x6E)) ? 1 : 0;
    }
#pragma unroll
    for (int m = 1; m < 64; m <<= 1) cnt += __shfl_xor(cnt, m);
    if (t == 0) *flag = (cnt > 1024) ? 1 : 0;
}

// ---------------------------------------------------------------------------
// Convert the four 1024x1024 weights to canonical bf16.
// ---------------------------------------------------------------------------
__global__ __launch_bounds__(256) void cvt_w4_kernel(
    const void* Wq, const void* Wk, const void* Wv, const void* Wout,
    unsigned short* dq, unsigned short* dk, unsigned short* dv, unsigned short* dout,
    const int* flagp) {
    const bool isf = (*flagp != 0);
    const void* s;
    unsigned short* d;
    switch (blockIdx.y) {
        case 0: s = Wq; d = dq; break;
        case 1: s = Wk; d = dk; break;
        case 2: s = Wv; d = dv; break;
        default: s = Wout; d = dout; break;
    }
    size_t i = ((size_t)blockIdx.x * 256 + threadIdx.x) * 4;
#pragma unroll
    for (int r = 0; r < 4; ++r) d[i + r] = f2us(loadAny(s, i + r, isf));
}

// ---------------------------------------------------------------------------
// Convert gate weights (3 x 8x1024 -> bf16) and biases (3 x 8 + 1024 -> f32).
// ---------------------------------------------------------------------------
__global__ __launch_bounds__(256) void cvt_small_kernel(
    const void* Wbeta, const void* Wig, const void* Wog,
    const void* bbeta, const void* big, const void* bog, const void* bout,
    unsigned short* dWb, unsigned short* dWi, unsigned short* dWo,
    float* dbb, float* dbi, float* dbo, float* dbout,
    const int* flagp) {
    const bool isf = (*flagp != 0);
    int gid = blockIdx.x * 256 + threadIdx.x;
    if (gid < 24576) {  // bf16 weight part
        int seg = gid >> 13, off = gid & 8191;
        const void* s = (seg == 0) ? Wbeta : (seg == 1) ? Wig : Wog;
        unsigned short* d = (seg == 0) ? dWb : (seg == 1) ? dWi : dWo;
        d[off] = f2us(loadAny(s, off, isf));
    } else {
        int j = gid - 24576;
        if (j < 8) dbb[j] = loadAny(bbeta, j, isf);
        else if (j < 16) dbi[j - 8] = loadAny(big, j - 8, isf);
        else if (j < 24) dbo[j - 16] = loadAny(bog, j - 16, isf);
        else if (j < 24 + 1024) dbout[j - 24] = loadAny(bout, j - 24, isf);
    }
}

// ---------------------------------------------------------------------------
// RoPE tables: cos/sin[l][i], i < 64, freq = l * theta^(-i/64)
// ---------------------------------------------------------------------------
__global__ __launch_bounds__(256) void rope_tables_kernel(float* __restrict__ cosT,
                                                          float* __restrict__ sinT) {
    int idx = blockIdx.x * 256 + threadIdx.x;  // 0 .. 4096*64-1
    int l = idx >> 6, i = idx & 63;
    float invf = powf(10000.0f, -(float)i * (1.0f / 64.0f));
    float fr = (float)l * invf;
    cosT[idx] = cosf(fr);
    sinT[idx] = sinf(fr);
}

// ---------------------------------------------------------------------------
// RMSNorm (dual-dtype input): h = x * rsqrt(mean(x^2)+1e-6) * w, h bf16.
// ---------------------------------------------------------------------------
__global__ __launch_bounds__(256) void rmsnorm_kernel(const void* __restrict__ xin,
                                                      const void* __restrict__ win,
                                                      __hip_bfloat16* __restrict__ h,
                                                      const int* __restrict__ flagp) {
    const bool isf = (*flagp != 0);
    const int row = blockIdx.x;
    const int tid = threadIdx.x;
    const int lane = tid & 63, wave = tid >> 6;
    const size_t base = (size_t)row * HID;
    float x0, x1, x2, x3;
    if (isf) {
        float4 u = ((const float4*)((const float*)xin + base))[tid];
        x0 = u.x; x1 = u.y; x2 = u.z; x3 = u.w;
    } else {
        ushort4 u = ((const ushort4*)((const unsigned short*)xin + base))[tid];
        x0 = bf2f(u.x); x1 = bf2f(u.y); x2 = bf2f(u.z); x3 = bf2f(u.w);
    }
    float ss = x0 * x0 + x1 * x1 + x2 * x2 + x3 * x3;
#pragma unroll
    for (int m = 1; m < 64; m <<= 1) ss += __shfl_xor(ss, m);
    __shared__ float wsum[4];
    if (lane == 0) wsum[wave] = ss;
    __syncthreads();
    float tot = wsum[0] + wsum[1] + wsum[2] + wsum[3];
    float inv = rsqrtf(tot * (1.0f / HID) + 1e-6f);
    float w0, w1, w2, w3;
    if (isf) {
        float4 u = ((const float4*)win)[tid];
        w0 = u.x; w1 = u.y; w2 = u.z; w3 = u.w;
    } else {
        ushort4 u = ((const ushort4*)win)[tid];
        w0 = bf2f(u.x); w1 = bf2f(u.y); w2 = bf2f(u.z); w3 = bf2f(u.w);
    }
    __hip_bfloat16* ho = h + base + tid * 4;
    ho[0] = __float2bfloat16(x0 * inv * w0);
    ho[1] = __float2bfloat16(x1 * inv * w1);
    ho[2] = __float2bfloat16(x2 * inv * w2);
    ho[3] = __float2bfloat16(x3 * inv * w3);
}

// ---------------------------------------------------------------------------
// Gates: sigmoid(h . Wg[hh] + bias) for 24 gates (beta, ig, og) per row.
// Weights bf16 (converted), biases f32 (converted). Output [bh][L] f32.
// ---------------------------------------------------------------------------
__global__ __launch_bounds__(256) void gates_kernel(
    const __hip_bfloat16* __restrict__ h,
    const __hip_bfloat16* __restrict__ Wbeta, const float* __restrict__ bbeta,
    const __hip_bfloat16* __restrict__ Wig, const float* __restrict__ big,
    const __hip_bfloat16* __restrict__ Wog, const float* __restrict__ bog,
    float* __restrict__ fT, float* __restrict__ gT, float* __restrict__ oT) {
    const int row = blockIdx.x;  // b*L + l
    const int tid = threadIdx.x;
    const int lane = tid & 63, wave = tid >> 6;
    const int b = row >> 12, l = row & (LQ - 1);
    const unsigned short* hp = (const unsigned short*)h + (size_t)row * HID + tid * 4;
    ushort4 hu = *(const ushort4*)hp;
    float h0 = bf2f(hu.x), h1 = bf2f(hu.y), h2 = bf2f(hu.z), h3 = bf2f(hu.w);
    float p[24];
#pragma unroll
    for (int g = 0; g < 24; ++g) {
        const __hip_bfloat16* wr = (g < 8) ? (Wbeta + g * HID)
                                 : (g < 16) ? (Wig + (g - 8) * HID)
                                            : (Wog + (g - 16) * HID);
        const unsigned short* wp = (const unsigned short*)wr + tid * 4;
        ushort4 wu = *(const ushort4*)wp;
        p[g] = h0 * bf2f(wu.x) + h1 * bf2f(wu.y) + h2 * bf2f(wu.z) + h3 * bf2f(wu.w);
    }
#pragma unroll
    for (int m = 1; m < 64; m <<= 1) {
#pragma unroll
        for (int g = 0; g < 24; ++g) p[g] += __shfl_xor(p[g], m);
    }
    __shared__ float part[4][24];
    if (lane == 0) {
#pragma unroll
        for (int g = 0; g < 24; ++g) part[wave][g] = p[g];
    }
    __syncthreads();
    if (tid < 24) {
        int g = tid;
        float s = part[0][g] + part[1][g] + part[2][g] + part[3][g];
        float bb = (g < 8) ? bbeta[g] : (g < 16) ? big[g - 8] : bog[g - 16];
        s += bb;
        s = 1.0f / (1.0f + expf(-s));
        int hh = (g < 8) ? g : (g < 16) ? g - 8 : g - 16;
        float* dst = (g < 8) ? fT : (g < 16) ? gT : oT;
        dst[((size_t)(b * NHEAD + hh)) * LQ + l] = s;
    }
}

// ---------------------------------------------------------------------------
// MFMA GEMM (m97 structure): C[M][N] = A[M][K] * W[N][K]^T (+bias).
// A,W bf16. Output bf16, or f32 when (dualOut && *flagp).
// ---------------------------------------------------------------------------
__global__ __launch_bounds__(256) void gemm_bt(const __hip_bfloat16* __restrict__ A,
                                               const __hip_bfloat16* __restrict__ W,
                                               const float* __restrict__ bias,
                                               void* __restrict__ C,
                                               int M, int N, int K,
                                               const int* __restrict__ flagp, int dualOut) {
    __shared__ unsigned short As[128 * 32];
    __shared__ unsigned short Bs[128 * 32];
    const bool f32out = (dualOut != 0) && (*flagp != 0);
    const int tid = threadIdx.x;
    const int lane = tid & 63, wave = tid >> 6;
    const int m0 = blockIdx.x * 128, n0 = blockIdx.y * 128;
    const int wm = (wave & 1) * 64, wn = (wave >> 1) * 64;
    const int lm = lane & 15, lq = lane >> 4;
    f32x4 acc[4][4] = {};
    const int c0 = tid, c1 = tid + 256;
    const int r0 = c0 >> 2, o0 = (c0 & 3) * 8;
    const int r1 = c1 >> 2, o1 = (c1 & 3) * 8;
    for (int k0 = 0; k0 < K; k0 += 32) {
        __builtin_amdgcn_global_load_lds(
            (const __attribute__((address_space(1))) void*)(A + (size_t)(m0 + r0) * K + k0 + o0),
            (__attribute__((address_space(3))) void*)(As + c0 * 8), 16, 0, 0);
        __builtin_amdgcn_global_load_lds(
            (const __attribute__((address_space(1))) void*)(A + (size_t)(m0 + r1) * K + k0 + o1),
            (__attribute__((address_space(3))) void*)(As + c1 * 8), 16, 0, 0);
        __builtin_amdgcn_global_load_lds(
            (const __attribute__((address_space(1))) void*)(W + (size_t)(n0 + r0) * K + k0 + o0),
            (__attribute__((address_space(3))) void*)(Bs + c0 * 8), 16, 0, 0);
        __builtin_amdgcn_global_load_lds(
            (const __attribute__((address_space(1))) void*)(W + (size_t)(n0 + r1) * K + k0 + o1),
            (__attribute__((address_space(3))) void*)(Bs + c1 * 8), 16, 0, 0);
        __syncthreads();
        bf16x8 af[4], bfr[4];
#pragma unroll
        for (int i = 0; i < 4; ++i)
            af[i] = *(const bf16x8*)(const void*)(As + (wm + i * 16 + lm) * 32 + lq * 8);
#pragma unroll
        for (int j = 0; j < 4; ++j)
            bfr[j] = *(const bf16x8*)(const void*)(Bs + (wn + j * 16 + lm) * 32 + lq * 8);
#pragma unroll
        for (int i = 0; i < 4; ++i)
#pragma unroll
            for (int j = 0; j < 4; ++j)
                acc[i][j] = __builtin_amdgcn_mfma_f32_16x16x32_bf16(af[i], bfr[j], acc[i][j], 0, 0, 0);
        __syncthreads();
    }
    // epilogue: C/D layout col = lane&15, row = (lane>>4)*4 + reg
#pragma unroll
    for (int i = 0; i < 4; ++i) {
#pragma unroll
        for (int j = 0; j < 4; ++j) {
            int col = n0 + wn + j * 16 + lm;
            float bv = bias ? bias[col] : 0.0f;
#pragma unroll
            for (int r = 0; r < 4; ++r) {
                int rowg = m0 + wm + i * 16 + lq * 4 + r;
                size_t idx = (size_t)rowg * N + col;
                float val = acc[i][j][r] + bv;
                if (f32out) ((float*)C)[idx] = val;
                else ((__hip_bfloat16*)C)[idx] = __float2bfloat16(val);
            }
        }
    }
}

// ---------------------------------------------------------------------------
// Scan: per (b,h) chain, M[d][e] (128x128 f32) recurrence, RoPE fused.
// Grid (8 esplit, 32 bh); wave lane = e(4) x dgrp(16); 8 M elems/thread.
// ---------------------------------------------------------------------------
__global__ __launch_bounds__(256) void scan_kernel(
    const __hip_bfloat16* __restrict__ qg, const __hip_bfloat16* __restrict__ kg,
    const __hip_bfloat16* __restrict__ vg,
    const float* __restrict__ fT, const float* __restrict__ gT, const float* __restrict__ oT,
    const float* __restrict__ cosT, const float* __restrict__ sinT,
    __hip_bfloat16* __restrict__ y) {
    const int esplit = blockIdx.x;  // 0..7
    const int bh = blockIdx.y;      // 0..31
    const int b = bh >> 3, hh = bh & 7;
    const int tid = threadIdx.x;
    const int lane = tid & 63, wave = tid >> 6;
    const int e_l = lane & 3, dgrp = lane >> 2;
    const int d0 = dgrp * 8;
    const int colv = wave * 4 + e_l;      // 0..15 within block
    const int ecol = esplit * 16 + colv;  // 0..127 within head
    __shared__ __align__(16) float qs[16][128];
    __shared__ __align__(16) float ks[16][128];
    __shared__ float vs[16][16];
    __shared__ float fs[16], osct[16];
    float M[8];
#pragma unroll
    for (int j = 0; j < 8; ++j) M[j] = 0.0f;
    const float scale = 0.08838834764831845f;  // 1/sqrt(128)
    const unsigned short* qp = (const unsigned short*)qg;
    const unsigned short* kp = (const unsigned short*)kg;
    const unsigned short* vp = (const unsigned short*)vg;

    for (int t0 = 0; t0 < LQ; t0 += 16) {
        __syncthreads();
#pragma unroll
        for (int r = 0; r < 4; ++r) {
            int pid = tid + r * 256;
            int t = pid >> 6, i = pid & 63;
            int gt = t0 + t;
            size_t gidx = ((size_t)(b * LQ + gt)) * HID + hh * DHEAD + i;
            float c = cosT[gt * 64 + i], s = sinT[gt * 64 + i];
            float q1 = bf2f(qp[gidx]), q2 = bf2f(qp[gidx + 64]);
            qs[t][i] = q1 * c - q2 * s;
            qs[t][i + 64] = q1 * s + q2 * c;
            float k1 = bf2f(kp[gidx]), k2 = bf2f(kp[gidx + 64]);
            ks[t][i] = k1 * c - k2 * s;
            ks[t][i + 64] = k1 * s + k2 * c;
        }
        {
            int t = tid >> 4, el = tid & 15;
            int gt = t0 + t;
            float gv = gT[(size_t)bh * LQ + gt];
            vs[t][el] = gv * scale *
                bf2f(vp[((size_t)(b * LQ + gt)) * HID + hh * DHEAD + esplit * 16 + el]);
        }
        if (tid < 16) {
            fs[tid] = fT[(size_t)bh * LQ + t0 + tid];
            osct[tid] = oT[(size_t)bh * LQ + t0 + tid];
        }
        __syncthreads();
#pragma unroll
        for (int t = 0; t < 16; ++t) {
            float f = fs[t];
            float a = vs[t][colv];
            float4 ka = *(const float4*)&ks[t][d0];
            float4 kb = *(const float4*)&ks[t][d0 + 4];
            float4 qa = *(const float4*)&qs[t][d0];
            float4 qb = *(const float4*)&qs[t][d0 + 4];
            float yp;
            M[0] = f * M[0] + a * ka.x;  yp  = qa.x * M[0];
            M[1] = f * M[1] + a * ka.y;  yp += qa.y * M[1];
            M[2] = f * M[2] + a * ka.z;  yp += qa.z * M[2];
            M[3] = f * M[3] + a * ka.w;  yp += qa.w * M[3];
            M[4] = f * M[4] + a * kb.x;  yp += qb.x * M[4];
            M[5] = f * M[5] + a * kb.y;  yp += qb.y * M[5];
            M[6] = f * M[6] + a * kb.z;  yp += qb.z * M[6];
            M[7] = f * M[7] + a * kb.w;  yp += qb.w * M[7];
            yp += __shfl_xor(yp, 4);
            yp += __shfl_xor(yp, 8);
            yp += __shfl_xor(yp, 16);
            yp += __shfl_xor(yp, 32);
            if (dgrp == 0) {
                y[((size_t)(b * LQ + t0 + t)) * HID + hh * DHEAD + ecol] =
                    __float2bfloat16(yp * osct[t]);
            }
        }
    }
}

// ---------------------------------------------------------------------------
extern "C" void kernel_launch(void* const* d_in, const int* in_sizes, int n_in,
                              void* d_out, int out_size, void* d_ws, size_t ws_size,
                              hipStream_t stream) {
    const void* x      = d_in[0];
    const void* norm_w = d_in[1];
    const void* Wq     = d_in[2];
    const void* Wk     = d_in[3];
    const void* Wv     = d_in[4];
    const void* Wbeta  = d_in[5];
    const void* bbeta  = d_in[6];
    const void* Wig    = d_in[7];
    const void* big    = d_in[8];
    const void* Wog    = d_in[9];
    const void* bog    = d_in[10];
    const void* Wout   = d_in[11];
    const void* bout   = d_in[12];

    char* ws = (char*)d_ws;
    const size_t KB = 1024, MB = 1024 * 1024;
    int*   flag    = (int*)(ws + 0);
    float* bbeta_c = (float*)(ws + 1 * KB);
    float* big_c   = (float*)(ws + 1 * KB + 32);
    float* bog_c   = (float*)(ws + 1 * KB + 64);
    float* bout_c  = (float*)(ws + 4 * KB);            // 4 KiB
    unsigned short* Wbeta_c = (unsigned short*)(ws + 64 * KB);   // 16 KiB each
    unsigned short* Wig_c   = (unsigned short*)(ws + 96 * KB);
    unsigned short* Wog_c   = (unsigned short*)(ws + 128 * KB);
    float* fT   = (float*)(ws + 1 * MB);               // 512 KiB each
    float* gT   = (float*)(ws + 1 * MB + 512 * KB);
    float* oT   = (float*)(ws + 2 * MB);
    float* cosT = (float*)(ws + 2 * MB + 512 * KB);    // 1 MiB each
    float* sinT = (float*)(ws + 3 * MB + 512 * KB);
    unsigned short* Wq_c   = (unsigned short*)(ws + 5 * MB);   // 2 MiB each
    unsigned short* Wk_c   = (unsigned short*)(ws + 7 * MB);
    unsigned short* Wv_c   = (unsigned short*)(ws + 9 * MB);
    unsigned short* Wout_c = (unsigned short*)(ws + 11 * MB);
    __hip_bfloat16* h  = (__hip_bfloat16*)(ws + 16 * MB);  // 32 MiB each
    __hip_bfloat16* qb = (__hip_bfloat16*)(ws + 48 * MB);
    __hip_bfloat16* kb = (__hip_bfloat16*)(ws + 80 * MB);
    __hip_bfloat16* vb = (__hip_bfloat16*)(ws + 112 * MB);
    __hip_bfloat16* yb = (__hip_bfloat16*)(ws + 144 * MB);

    detect_kernel<<<1, 64, 0, stream>>>(x, flag);
    cvt_w4_kernel<<<dim3(1024, 4), 256, 0, stream>>>(Wq, Wk, Wv, Wout,
                                                     Wq_c, Wk_c, Wv_c, Wout_c, flag);
    cvt_small_kernel<<<101, 256, 0, stream>>>(Wbeta, Wig, Wog, bbeta, big, bog, bout,
                                              Wbeta_c, Wig_c, Wog_c,
                                              bbeta_c, big_c, bog_c, bout_c, flag);
    rope_tables_kernel<<<(LQ * 64) / 256, 256, 0, stream>>>(cosT, sinT);
    rmsnorm_kernel<<<MROWS, 256, 0, stream>>>(x, norm_w, h, flag);
    gates_kernel<<<MROWS, 256, 0, stream>>>(h, (const __hip_bfloat16*)Wbeta_c, bbeta_c,
                                            (const __hip_bfloat16*)Wig_c, big_c,
                                            (const __hip_bfloat16*)Wog_c, bog_c, fT, gT, oT);

    dim3 gg(MROWS / 128, HID / 128);
    gemm_bt<<<gg, 256, 0, stream>>>(h, (const __hip_bfloat16*)Wq_c, nullptr, qb,
                                    MROWS, HID, HID, flag, 0);
    gemm_bt<<<gg, 256, 0, stream>>>(h, (const __hip_bfloat16*)Wk_c, nullptr, kb,
                                    MROWS, HID, HID, flag, 0);
    gemm_bt<<<gg, 256, 0, stream>>>(h, (const __hip_bfloat16*)Wv_c, nullptr, vb,
                                    MROWS, HID, HID, flag, 0);

    scan_kernel<<<dim3(8, 32), 256, 0, stream>>>(qb, kb, vb, fT, gT, oT, cosT, sinT, yb);

    gemm_bt<<<gg, 256, 0, stream>>>(yb, (const __hip_bfloat16*)Wout_c, bout_c, d_out,
                                    MROWS, HID, HID, flag, 1);
}

// Round 3
// 783.955 us; speedup vs baseline: 2.0289x; 2.0289x over previous
//
#include <hip/hip_runtime.h>
#include <hip/hip_bf16.h>

#define BQ 4
#define LQ 4096
#define HID 1024
#define NHEAD 8
#define DHEAD 128
#define MROWS (BQ * LQ) /* 16384 */
#define CCH 64          /* chunk length */
#define NCH (LQ / CCH)  /* 64 chunks */

typedef __bf16 bf16x8 __attribute__((ext_vector_type(8)));
typedef float f32x4 __attribute__((ext_vector_type(4)));

__device__ __forceinline__ float bf2f(unsigned short u) {
    return __uint_as_float(((unsigned int)u) << 16);
}
__device__ __forceinline__ unsigned short f2us(float f) {
    __hip_bfloat16 b = __float2bfloat16(f);
    return *reinterpret_cast<unsigned short*>(&b);
}
__device__ __forceinline__ float loadAny(const void* p, size_t i, bool isf) {
    return isf ? ((const float*)p)[i] : bf2f(((const unsigned short*)p)[i]);
}

// ---------------------------------------------------------------------------
// Dtype probe: flag=1 -> inputs are f32; flag=0 -> bf16. (see round-1 notes)
// ---------------------------------------------------------------------------
__global__ void detect_kernel(const void* x, int* flag) {
    const unsigned short* u = (const unsigned short*)x;
    int t = threadIdx.x;  // 64 threads
    int cnt = 0;
#pragma unroll
    for (int s = 0; s < 64; ++s) {
        unsigned short v = u[2 * (t * 64 + s)];
        int e = (v >> 7) & 0xFF;
        cnt += (e >= 0x8A || (e != 0 && e <= 0x6E)) ? 1 : 0;
    }
#pragma unroll
    for (int m = 1; m < 64; m <<= 1) cnt += __shfl_xor(cnt, m);
    if (t == 0) *flag = (cnt > 1024) ? 1 : 0;
}

// ---------------------------------------------------------------------------
// Convert the four 1024x1024 weights to canonical bf16.
// ---------------------------------------------------------------------------
__global__ __launch_bounds__(256) void cvt_w4_kernel(
    const void* Wq, const void* Wk, const void* Wv, const void* Wout,
    unsigned short* dq, unsigned short* dk, unsigned short* dv, unsigned short* dout,
    const int* flagp) {
    const bool isf = (*flagp != 0);
    const void* s;
    unsigned short* d;
    switch (blockIdx.y) {
        case 0: s = Wq; d = dq; break;
        case 1: s = Wk; d = dk; break;
        case 2: s = Wv; d = dv; break;
        default: s = Wout; d = dout; break;
    }
    size_t i = ((size_t)blockIdx.x * 256 + threadIdx.x) * 4;
#pragma unroll
    for (int r = 0; r < 4; ++r) d[i + r] = f2us(loadAny(s, i + r, isf));
}

// ---------------------------------------------------------------------------
// Convert gate weights (3 x 8x1024 -> bf16) and biases (-> f32).
// ---------------------------------------------------------------------------
__global__ __launch_bounds__(256) void cvt_small_kernel(
    const void* Wbeta, const void* Wig, const void* Wog,
    const void* bbeta, const void* big, const void* bog, const void* bout,
    unsigned short* dWb, unsigned short* dWi, unsigned short* dWo,
    float* dbb, float* dbi, float* dbo, float* dbout,
    const int* flagp) {
    const bool isf = (*flagp != 0);
    int gid = blockIdx.x * 256 + threadIdx.x;
    if (gid < 24576) {
        int seg = gid >> 13, off = gid & 8191;
        const void* s = (seg == 0) ? Wbeta : (seg == 1) ? Wig : Wog;
        unsigned short* d = (seg == 0) ? dWb : (seg == 1) ? dWi : dWo;
        d[off] = f2us(loadAny(s, off, isf));
    } else {
        int j = gid - 24576;
        if (j < 8) dbb[j] = loadAny(bbeta, j, isf);
        else if (j < 16) dbi[j - 8] = loadAny(big, j - 8, isf);
        else if (j < 24) dbo[j - 16] = loadAny(bog, j - 16, isf);
        else if (j < 24 + 1024) dbout[j - 24] = loadAny(bout, j - 24, isf);
    }
}

// ---------------------------------------------------------------------------
// RoPE tables: cos/sin[l][i], i < 64
// ---------------------------------------------------------------------------
__global__ __launch_bounds__(256) void rope_tables_kernel(float* __restrict__ cosT,
                                                          float* __restrict__ sinT) {
    int idx = blockIdx.x * 256 + threadIdx.x;
    int l = idx >> 6, i = idx & 63;
    float invf = powf(10000.0f, -(float)i * (1.0f / 64.0f));
    float fr = (float)l * invf;
    cosT[idx] = cosf(fr);
    sinT[idx] = sinf(fr);
}

// ---------------------------------------------------------------------------
// RMSNorm (dual-dtype input): h = x * rsqrt(mean(x^2)+1e-6) * w, h bf16.
// ---------------------------------------------------------------------------
__global__ __launch_bounds__(256) void rmsnorm_kernel(const void* __restrict__ xin,
                                                      const void* __restrict__ win,
                                                      __hip_bfloat16* __restrict__ h,
                                                      const int* __restrict__ flagp) {
    const bool isf = (*flagp != 0);
    const int row = blockIdx.x;
    const int tid = threadIdx.x;
    const int lane = tid & 63, wave = tid >> 6;
    const size_t base = (size_t)row * HID;
    float x0, x1, x2, x3;
    if (isf) {
        float4 u = ((const float4*)((const float*)xin + base))[tid];
        x0 = u.x; x1 = u.y; x2 = u.z; x3 = u.w;
    } else {
        ushort4 u = ((const ushort4*)((const unsigned short*)xin + base))[tid];
        x0 = bf2f(u.x); x1 = bf2f(u.y); x2 = bf2f(u.z); x3 = bf2f(u.w);
    }
    float ss = x0 * x0 + x1 * x1 + x2 * x2 + x3 * x3;
#pragma unroll
    for (int m = 1; m < 64; m <<= 1) ss += __shfl_xor(ss, m);
    __shared__ float wsum[4];
    if (lane == 0) wsum[wave] = ss;
    __syncthreads();
    float tot = wsum[0] + wsum[1] + wsum[2] + wsum[3];
    float inv = rsqrtf(tot * (1.0f / HID) + 1e-6f);
    float w0, w1, w2, w3;
    if (isf) {
        float4 u = ((const float4*)win)[tid];
        w0 = u.x; w1 = u.y; w2 = u.z; w3 = u.w;
    } else {
        ushort4 u = ((const ushort4*)win)[tid];
        w0 = bf2f(u.x); w1 = bf2f(u.y); w2 = bf2f(u.z); w3 = bf2f(u.w);
    }
    __hip_bfloat16* ho = h + base + tid * 4;
    ho[0] = __float2bfloat16(x0 * inv * w0);
    ho[1] = __float2bfloat16(x1 * inv * w1);
    ho[2] = __float2bfloat16(x2 * inv * w2);
    ho[3] = __float2bfloat16(x3 * inv * w3);
}

// ---------------------------------------------------------------------------
// Gates: sigmoid(h . Wg[hh] + bias), output [bh][L] f32.
// ---------------------------------------------------------------------------
__global__ __launch_bounds__(256) void gates_kernel(
    const __hip_bfloat16* __restrict__ h,
    const __hip_bfloat16* __restrict__ Wbeta, const float* __restrict__ bbeta,
    const __hip_bfloat16* __restrict__ Wig, const float* __restrict__ big,
    const __hip_bfloat16* __restrict__ Wog, const float* __restrict__ bog,
    float* __restrict__ fT, float* __restrict__ gT, float* __restrict__ oT) {
    const int row = blockIdx.x;
    const int tid = threadIdx.x;
    const int lane = tid & 63, wave = tid >> 6;
    const int b = row >> 12, l = row & (LQ - 1);
    const unsigned short* hp = (const unsigned short*)h + (size_t)row * HID + tid * 4;
    ushort4 hu = *(const ushort4*)hp;
    float h0 = bf2f(hu.x), h1 = bf2f(hu.y), h2 = bf2f(hu.z), h3 = bf2f(hu.w);
    float p[24];
#pragma unroll
    for (int g = 0; g < 24; ++g) {
        const __hip_bfloat16* wr = (g < 8) ? (Wbeta + g * HID)
                                 : (g < 16) ? (Wig + (g - 8) * HID)
                                            : (Wog + (g - 16) * HID);
        const unsigned short* wp = (const unsigned short*)wr + tid * 4;
        ushort4 wu = *(const ushort4*)wp;
        p[g] = h0 * bf2f(wu.x) + h1 * bf2f(wu.y) + h2 * bf2f(wu.z) + h3 * bf2f(wu.w);
    }
#pragma unroll
    for (int m = 1; m < 64; m <<= 1) {
#pragma unroll
        for (int g = 0; g < 24; ++g) p[g] += __shfl_xor(p[g], m);
    }
    __shared__ float part[4][24];
    if (lane == 0) {
#pragma unroll
        for (int g = 0; g < 24; ++g) part[wave][g] = p[g];
    }
    __syncthreads();
    if (tid < 24) {
        int g = tid;
        float s = part[0][g] + part[1][g] + part[2][g] + part[3][g];
        float bb = (g < 8) ? bbeta[g] : (g < 16) ? big[g - 8] : bog[g - 16];
        s += bb;
        s = 1.0f / (1.0f + expf(-s));
        int hh = (g < 8) ? g : (g < 16) ? g - 8 : g - 16;
        float* dst = (g < 8) ? fT : (g < 16) ? gT : oT;
        dst[((size_t)(b * NHEAD + hh)) * LQ + l] = s;
    }
}

// ---------------------------------------------------------------------------
// MFMA GEMM (m97 structure): C[M][N] = A[M][K] * W[N][K]^T (+bias).
// ---------------------------------------------------------------------------
__global__ __launch_bounds__(256) void gemm_bt(const __hip_bfloat16* __restrict__ A,
                                               const __hip_bfloat16* __restrict__ W,
                                               const float* __restrict__ bias,
                                               void* __restrict__ C,
                                               int M, int N, int K,
                                               const int* __restrict__ flagp, int dualOut) {
    __shared__ unsigned short As[128 * 32];
    __shared__ unsigned short Bs[128 * 32];
    const bool f32out = (dualOut != 0) && (*flagp != 0);
    const int tid = threadIdx.x;
    const int lane = tid & 63, wave = tid >> 6;
    const int m0 = blockIdx.x * 128, n0 = blockIdx.y * 128;
    const int wm = (wave & 1) * 64, wn = (wave >> 1) * 64;
    const int lm = lane & 15, lq = lane >> 4;
    f32x4 acc[4][4] = {};
    const int c0 = tid, c1 = tid + 256;
    const int r0 = c0 >> 2, o0 = (c0 & 3) * 8;
    const int r1 = c1 >> 2, o1 = (c1 & 3) * 8;
    for (int k0 = 0; k0 < K; k0 += 32) {
        __builtin_amdgcn_global_load_lds(
            (const __attribute__((address_space(1))) void*)(A + (size_t)(m0 + r0) * K + k0 + o0),
            (__attribute__((address_space(3))) void*)(As + c0 * 8), 16, 0, 0);
        __builtin_amdgcn_global_load_lds(
            (const __attribute__((address_space(1))) void*)(A + (size_t)(m0 + r1) * K + k0 + o1),
            (__attribute__((address_space(3))) void*)(As + c1 * 8), 16, 0, 0);
        __builtin_amdgcn_global_load_lds(
            (const __attribute__((address_space(1))) void*)(W + (size_t)(n0 + r0) * K + k0 + o0),
            (__attribute__((address_space(3))) void*)(Bs + c0 * 8), 16, 0, 0);
        __builtin_amdgcn_global_load_lds(
            (const __attribute__((address_space(1))) void*)(W + (size_t)(n0 + r1) * K + k0 + o1),
            (__attribute__((address_space(3))) void*)(Bs + c1 * 8), 16, 0, 0);
        __syncthreads();
        bf16x8 af[4], bfr[4];
#pragma unroll
        for (int i = 0; i < 4; ++i)
            af[i] = *(const bf16x8*)(const void*)(As + (wm + i * 16 + lm) * 32 + lq * 8);
#pragma unroll
        for (int j = 0; j < 4; ++j)
            bfr[j] = *(const bf16x8*)(const void*)(Bs + (wn + j * 16 + lm) * 32 + lq * 8);
#pragma unroll
        for (int i = 0; i < 4; ++i)
#pragma unroll
            for (int j = 0; j < 4; ++j)
                acc[i][j] = __builtin_amdgcn_mfma_f32_16x16x32_bf16(af[i], bfr[j], acc[i][j], 0, 0, 0);
        __syncthreads();
    }
#pragma unroll
    for (int i = 0; i < 4; ++i) {
#pragma unroll
        for (int j = 0; j < 4; ++j) {
            int col = n0 + wn + j * 16 + lm;
            float bv = bias ? bias[col] : 0.0f;
#pragma unroll
            for (int r = 0; r < 4; ++r) {
                int rowg = m0 + wm + i * 16 + lq * 4 + r;
                size_t idx = (size_t)rowg * N + col;
                float val = acc[i][j][r] + bv;
                if (f32out) ((float*)C)[idx] = val;
                else ((__hip_bfloat16*)C)[idx] = __float2bfloat16(val);
            }
        }
    }
}

// ---------------------------------------------------------------------------
// INTRA kernel: per (chunk, bh) block. Computes the causal within-chunk part
//   Y_intra[j] = sum_{s<=j} exp(Lp_j-Lp_s) * a_s * (q_j.k_s) * v_s
// entirely with MFMA, writes o_j * Y_intra into yb. Fully parallel (2048 blks).
// LDS strides: 136 (K=128 ops) / 72 (K=64 ops) -> 2-way bank spread (free).
// ---------------------------------------------------------------------------
__global__ __launch_bounds__(256) void intra_kernel(
    const __hip_bfloat16* __restrict__ qg, const __hip_bfloat16* __restrict__ kg,
    const __hip_bfloat16* __restrict__ vg,
    const float* __restrict__ fT, const float* __restrict__ gT, const float* __restrict__ oT,
    const float* __restrict__ cosT, const float* __restrict__ sinT,
    __hip_bfloat16* __restrict__ yb) {
    const int chunk = blockIdx.x;        // 0..63
    const int bh = blockIdx.y;           // 0..31
    const int b = bh >> 3, hh = bh & 7;
    const int t0 = chunk * CCH;
    const int tid = threadIdx.x;
    const int lane = tid & 63, wave = tid >> 6;
    const int lm = lane & 15, lq = lane >> 4;
    __shared__ unsigned short Qr[64 * 136];
    __shared__ unsigned short Kr[64 * 136];
    __shared__ unsigned short Vt[128 * 72];
    __shared__ unsigned short Sp[64 * 72];
    __shared__ float Lp[64], aS[64], osh[64];
    const unsigned short* qp = (const unsigned short*)qg;
    const unsigned short* kp = (const unsigned short*)kg;
    const unsigned short* vp = (const unsigned short*)vg;

    // gate loads + log-decay prefix (wave 0 only)
    if (tid < 64) {
        float f = fT[(size_t)bh * LQ + t0 + tid];
        float g = gT[(size_t)bh * LQ + t0 + tid];
        osh[tid] = oT[(size_t)bh * LQ + t0 + tid];
        float lf = __logf(f);
#pragma unroll
        for (int off = 1; off < 64; off <<= 1) {
            float v = __shfl_up(lf, off);
            if (lane >= off) lf += v;
        }
        Lp[tid] = lf;
        aS[tid] = g * 0.08838834764831845f;  // g / sqrt(128)
    }
    // stage q,k with RoPE (raw, unscaled)
#pragma unroll
    for (int r = 0; r < 16; ++r) {
        int lin = r * 256 + tid;
        int t = lin >> 6, i = lin & 63;
        int gt = t0 + t;
        size_t gidx = ((size_t)(b * LQ + gt)) * HID + hh * DHEAD + i;
        float c = cosT[gt * 64 + i], s = sinT[gt * 64 + i];
        float q1 = bf2f(qp[gidx]), q2 = bf2f(qp[gidx + 64]);
        Qr[t * 136 + i] = f2us(q1 * c - q2 * s);
        Qr[t * 136 + i + 64] = f2us(q1 * s + q2 * c);
        float k1 = bf2f(kp[gidx]), k2 = bf2f(kp[gidx + 64]);
        Kr[t * 136 + i] = f2us(k1 * c - k2 * s);
        Kr[t * 136 + i + 64] = f2us(k1 * s + k2 * c);
    }
    // stage V transposed: Vt[e][s]
#pragma unroll
    for (int r = 0; r < 32; ++r) {
        int lin = r * 256 + tid;
        int sI = lin >> 7, e = lin & 127;
        float val = bf2f(vp[((size_t)(b * LQ + t0 + sI)) * HID + hh * DHEAD + e]);
        Vt[e * 72 + sI] = f2us(val);
    }
    __syncthreads();
    // S = Q K^T (64x64, K=128); wave handles j-strip [16*wave, +16)
    f32x4 sacc[4] = {};
#pragma unroll
    for (int ks = 0; ks < 4; ++ks) {
        bf16x8 af = *(const bf16x8*)(const void*)(Qr + (16 * wave + lm) * 136 + ks * 32 + lq * 8);
#pragma unroll
        for (int nt = 0; nt < 4; ++nt) {
            bf16x8 bf = *(const bf16x8*)(const void*)(Kr + (nt * 16 + lm) * 136 + ks * 32 + lq * 8);
            sacc[nt] = __builtin_amdgcn_mfma_f32_16x16x32_bf16(af, bf, sacc[nt], 0, 0, 0);
        }
    }
    // mask + decay/gate scale, store S' bf16 [j][s]
#pragma unroll
    for (int nt = 0; nt < 4; ++nt) {
#pragma unroll
        for (int r = 0; r < 4; ++r) {
            int j = 16 * wave + lq * 4 + r;
            int s = nt * 16 + lm;
            float v = 0.0f;
            if (j >= s) v = sacc[nt][r] * __expf(Lp[j] - Lp[s]) * aS[s];
            Sp[j * 72 + s] = f2us(v);
        }
    }
    __syncthreads();
    // Y_intra = S' V  (64x128, K=64)
    f32x4 ya[8] = {};
#pragma unroll
    for (int ks = 0; ks < 2; ++ks) {
        bf16x8 af = *(const bf16x8*)(const void*)(Sp + (16 * wave + lm) * 72 + ks * 32 + lq * 8);
#pragma unroll
        for (int nt = 0; nt < 8; ++nt) {
            bf16x8 bf = *(const bf16x8*)(const void*)(Vt + (nt * 16 + lm) * 72 + ks * 32 + lq * 8);
            ya[nt] = __builtin_amdgcn_mfma_f32_16x16x32_bf16(af, bf, ya[nt], 0, 0, 0);
        }
    }
    // epilogue: yb = o_j * Y_intra
#pragma unroll
    for (int nt = 0; nt < 8; ++nt) {
#pragma unroll
        for (int r = 0; r < 4; ++r) {
            int j = 16 * wave + lq * 4 + r;
            int e = nt * 16 + lm;
            size_t row = (size_t)(b * LQ + t0 + j);
            yb[row * HID + hh * DHEAD + e] = __float2bfloat16(osh[j] * ya[nt][r]);
        }
    }
}

// ---------------------------------------------------------------------------
// INTER kernel: sequential over 64 chunks. Block = (bh, esplit): owns state
// M[d=128][e=16] f32 in LDS. Per chunk:
//   Y_inter = (exp(Lp_j) * Q) @ M       (MFMA, 64x16, K=128)
//   U       = K''^T V                   (MFMA, 128x16, K=64), K''[s]=exp(Lp63-Lp_s)*a_s*k_s
//   yb     += o * Y_inter ;  M = exp(Lp63)*M + U
// grid (32, 8): the 8 e-split twins of a chain are 32 apart in linear block
// id -> same XCD under round-robin -> L2-dedup of q/k chunk reads.
// ---------------------------------------------------------------------------
__global__ __launch_bounds__(256) void inter_kernel(
    const __hip_bfloat16* __restrict__ qg, const __hip_bfloat16* __restrict__ kg,
    const __hip_bfloat16* __restrict__ vg,
    const float* __restrict__ fT, const float* __restrict__ gT, const float* __restrict__ oT,
    const float* __restrict__ cosT, const float* __restrict__ sinT,
    __hip_bfloat16* __restrict__ yb) {
    const int bh = blockIdx.x;       // 0..31
    const int esplit = blockIdx.y;   // 0..7
    const int e0 = esplit * 16;
    const int b = bh >> 3, hh = bh & 7;
    const int tid = threadIdx.x;
    const int lane = tid & 63, wave = tid >> 6;
    const int lm = lane & 15, lq = lane >> 4;
    __shared__ unsigned short Qsl[64 * 136];  // scaled+rope'd q
    __shared__ unsigned short Ktl[128 * 72];  // K'' transposed [d][s]
    __shared__ unsigned short Vtl[16 * 72];   // V-slice transposed [e][s]
    __shared__ float Ml[16 * 132];            // state M^T: [e][d], stride 132
    __shared__ float w2s[64], qscs[64], osh[64], cdecS[1];
    const unsigned short* qp = (const unsigned short*)qg;
    const unsigned short* kp = (const unsigned short*)kg;
    const unsigned short* vp = (const unsigned short*)vg;
    unsigned short* ybp = (unsigned short*)yb;

    for (int i = tid; i < 16 * 132; i += 256) Ml[i] = 0.0f;

    for (int c = 0; c < NCH; ++c) {
        const int t0 = c * CCH;
        // gates + decay prefix (wave 0)
        if (tid < 64) {
            float f = fT[(size_t)bh * LQ + t0 + tid];
            float g = gT[(size_t)bh * LQ + t0 + tid];
            osh[tid] = oT[(size_t)bh * LQ + t0 + tid];
            float lf = __logf(f);
#pragma unroll
            for (int off = 1; off < 64; off <<= 1) {
                float v = __shfl_up(lf, off);
                if (lane >= off) lf += v;
            }
            float tot = __shfl(lf, 63);
            w2s[tid] = __expf(tot - lf) * (g * 0.08838834764831845f);
            qscs[tid] = __expf(lf);
            if (tid == 63) cdecS[0] = __expf(lf);
        }
        __syncthreads();  // B1
        // stage Qsl = exp(Lp_j) * rope(q)
#pragma unroll
        for (int r = 0; r < 16; ++r) {
            int lin = r * 256 + tid;
            int j = lin >> 6, i = lin & 63;
            int gt = t0 + j;
            size_t gidx = ((size_t)(b * LQ + gt)) * HID + hh * DHEAD + i;
            float cc = cosT[gt * 64 + i], ss = sinT[gt * 64 + i];
            float q1 = bf2f(qp[gidx]), q2 = bf2f(qp[gidx + 64]);
            float sc = qscs[j];
            Qsl[j * 136 + i] = f2us((q1 * cc - q2 * ss) * sc);
            Qsl[j * 136 + i + 64] = f2us((q1 * ss + q2 * cc) * sc);
        }
        // stage Ktl[d][s] = w2[s] * rope(k)
#pragma unroll
        for (int r = 0; r < 16; ++r) {
            int lin = r * 256 + tid;
            int sI = lin >> 6, i = lin & 63;
            int gt = t0 + sI;
            size_t gidx = ((size_t)(b * LQ + gt)) * HID + hh * DHEAD + i;
            float cc = cosT[gt * 64 + i], ss = sinT[gt * 64 + i];
            float k1 = bf2f(kp[gidx]), k2 = bf2f(kp[gidx + 64]);
            float wsc = w2s[sI];
            Ktl[i * 72 + sI] = f2us((k1 * cc - k2 * ss) * wsc);
            Ktl[(i + 64) * 72 + sI] = f2us((k1 * ss + k2 * cc) * wsc);
        }
        // stage Vtl[e][s] (this block's 16 e-columns)
#pragma unroll
        for (int r = 0; r < 4; ++r) {
            int lin = r * 256 + tid;
            int sI = lin >> 4, e = lin & 15;
            float val = bf2f(vp[((size_t)(b * LQ + t0 + sI)) * HID + hh * DHEAD + e0 + e]);
            Vtl[e * 72 + sI] = f2us(val);
        }
        __syncthreads();  // B2
        float cd = cdecS[0];
        // U = K''^T V : wave covers d-strip [32*wave, +32), 2 m-tiles
        f32x4 uacc[2] = {};
#pragma unroll
        for (int ks = 0; ks < 2; ++ks) {
            bf16x8 bf = *(const bf16x8*)(const void*)(Vtl + lm * 72 + ks * 32 + lq * 8);
#pragma unroll
            for (int mt = 0; mt < 2; ++mt) {
                bf16x8 af = *(const bf16x8*)(const void*)(Ktl + (32 * wave + 16 * mt + lm) * 72 + ks * 32 + lq * 8);
                uacc[mt] = __builtin_amdgcn_mfma_f32_16x16x32_bf16(af, bf, uacc[mt], 0, 0, 0);
            }
        }
        // Y_inter = Qs @ M : wave j-strip [16*wave, +16)
        f32x4 yacc = {};
#pragma unroll
        for (int ks = 0; ks < 4; ++ks) {
            bf16x8 af = *(const bf16x8*)(const void*)(Qsl + (16 * wave + lm) * 136 + ks * 32 + lq * 8);
            float4 m0 = *(const float4*)(const void*)(Ml + lm * 132 + ks * 32 + lq * 8);
            float4 m1 = *(const float4*)(const void*)(Ml + lm * 132 + ks * 32 + lq * 8 + 4);
            unsigned short tmp[8];
            tmp[0] = f2us(m0.x); tmp[1] = f2us(m0.y); tmp[2] = f2us(m0.z); tmp[3] = f2us(m0.w);
            tmp[4] = f2us(m1.x); tmp[5] = f2us(m1.y); tmp[6] = f2us(m1.z); tmp[7] = f2us(m1.w);
            bf16x8 bfm = *(const bf16x8*)tmp;
            yacc = __builtin_amdgcn_mfma_f32_16x16x32_bf16(af, bfm, yacc, 0, 0, 0);
        }
        // yb += o * Y_inter
#pragma unroll
        for (int r = 0; r < 4; ++r) {
            int j = 16 * wave + lq * 4 + r;
            size_t idx = ((size_t)(b * LQ + t0 + j)) * HID + hh * DHEAD + e0 + lm;
            float prev = bf2f(ybp[idx]);
            ybp[idx] = f2us(prev + osh[j] * yacc[r]);
        }
        __syncthreads();  // B3 (all Ml/LDS reads done)
        // M = cdec * M + U
#pragma unroll
        for (int mt = 0; mt < 2; ++mt) {
#pragma unroll
            for (int r = 0; r < 4; ++r) {
                int d = 32 * wave + 16 * mt + lq * 4 + r;
                Ml[lm * 132 + d] = cd * Ml[lm * 132 + d] + uacc[mt][r];
            }
        }
    }
}

// ---------------------------------------------------------------------------
extern "C" void kernel_launch(void* const* d_in, const int* in_sizes, int n_in,
                              void* d_out, int out_size, void* d_ws, size_t ws_size,
                              hipStream_t stream) {
    const void* x      = d_in[0];
    const void* norm_w = d_in[1];
    const void* Wq     = d_in[2];
    const void* Wk     = d_in[3];
    const void* Wv     = d_in[4];
    const void* Wbeta  = d_in[5];
    const void* bbeta  = d_in[6];
    const void* Wig    = d_in[7];
    const void* big    = d_in[8];
    const void* Wog    = d_in[9];
    const void* bog    = d_in[10];
    const void* Wout   = d_in[11];
    const void* bout   = d_in[12];

    char* ws = (char*)d_ws;
    const size_t KB = 1024, MB = 1024 * 1024;
    int*   flag    = (int*)(ws + 0);
    float* bbeta_c = (float*)(ws + 1 * KB);
    float* big_c   = (float*)(ws + 1 * KB + 32);
    float* bog_c   = (float*)(ws + 1 * KB + 64);
    float* bout_c  = (float*)(ws + 4 * KB);
    unsigned short* Wbeta_c = (unsigned short*)(ws + 64 * KB);
    unsigned short* Wig_c   = (unsigned short*)(ws + 96 * KB);
    unsigned short* Wog_c   = (unsigned short*)(ws + 128 * KB);
    float* fT   = (float*)(ws + 1 * MB);
    float* gT   = (float*)(ws + 1 * MB + 512 * KB);
    float* oT   = (float*)(ws + 2 * MB);
    float* cosT = (float*)(ws + 2 * MB + 512 * KB);
    float* sinT = (float*)(ws + 3 * MB + 512 * KB);
    unsigned short* Wq_c   = (unsigned short*)(ws + 5 * MB);
    unsigned short* Wk_c   = (unsigned short*)(ws + 7 * MB);
    unsigned short* Wv_c   = (unsigned short*)(ws + 9 * MB);
    unsigned short* Wout_c = (unsigned short*)(ws + 11 * MB);
    __hip_bfloat16* h  = (__hip_bfloat16*)(ws + 16 * MB);
    __hip_bfloat16* qb = (__hip_bfloat16*)(ws + 48 * MB);
    __hip_bfloat16* kb = (__hip_bfloat16*)(ws + 80 * MB);
    __hip_bfloat16* vb = (__hip_bfloat16*)(ws + 112 * MB);
    __hip_bfloat16* yb = (__hip_bfloat16*)(ws + 144 * MB);

    detect_kernel<<<1, 64, 0, stream>>>(x, flag);
    cvt_w4_kernel<<<dim3(1024, 4), 256, 0, stream>>>(Wq, Wk, Wv, Wout,
                                                     Wq_c, Wk_c, Wv_c, Wout_c, flag);
    cvt_small_kernel<<<101, 256, 0, stream>>>(Wbeta, Wig, Wog, bbeta, big, bog, bout,
                                              Wbeta_c, Wig_c, Wog_c,
                                              bbeta_c, big_c, bog_c, bout_c, flag);
    rope_tables_kernel<<<(LQ * 64) / 256, 256, 0, stream>>>(cosT, sinT);
    rmsnorm_kernel<<<MROWS, 256, 0, stream>>>(x, norm_w, h, flag);
    gates_kernel<<<MROWS, 256, 0, stream>>>(h, (const __hip_bfloat16*)Wbeta_c, bbeta_c,
                                            (const __hip_bfloat16*)Wig_c, big_c,
                                            (const __hip_bfloat16*)Wog_c, bog_c, fT, gT, oT);

    dim3 gg(MROWS / 128, HID / 128);
    gemm_bt<<<gg, 256, 0, stream>>>(h, (const __hip_bfloat16*)Wq_c, nullptr, qb,
                                    MROWS, HID, HID, flag, 0);
    gemm_bt<<<gg, 256, 0, stream>>>(h, (const __hip_bfloat16*)Wk_c, nullptr, kb,
                                    MROWS, HID, HID, flag, 0);
    gemm_bt<<<gg, 256, 0, stream>>>(h, (const __hip_bfloat16*)Wv_c, nullptr, vb,
                                    MROWS, HID, HID, flag, 0);

    intra_kernel<<<dim3(NCH, 32), 256, 0, stream>>>(qb, kb, vb, fT, gT, oT, cosT, sinT, yb);
    inter_kernel<<<dim3(32, 8), 256, 0, stream>>>(qb, kb, vb, fT, gT, oT, cosT, sinT, yb);

    gemm_bt<<<gg, 256, 0, stream>>>(yb, (const __hip_bfloat16*)Wout_c, bout_c, d_out,
                                    MROWS, HID, HID, flag, 1);
}

// Round 5
// 609.814 us; speedup vs baseline: 2.6082x; 1.2856x over previous
//
#include <hip/hip_runtime.h>
#include <hip/hip_bf16.h>

#define BQ 4
#define LQ 4096
#define HID 1024
#define NHEAD 8
#define DHEAD 128
#define MROWS (BQ * LQ) /* 16384 */
#define CCH 64          /* chunk length */
#define NCH (LQ / CCH)  /* 64 chunks */

typedef __bf16 bf16x8 __attribute__((ext_vector_type(8)));
typedef float f32x4 __attribute__((ext_vector_type(4)));

__device__ __forceinline__ float bf2f(unsigned short u) {
    return __uint_as_float(((unsigned int)u) << 16);
}
__device__ __forceinline__ unsigned short f2us(float f) {
    __hip_bfloat16 b = __float2bfloat16(f);
    return *reinterpret_cast<unsigned short*>(&b);
}
__device__ __forceinline__ float loadAny(const void* p, size_t i, bool isf) {
    return isf ? ((const float*)p)[i] : bf2f(((const unsigned short*)p)[i]);
}

// ---------------------------------------------------------------------------
// Dtype probe: flag=1 -> inputs are f32; flag=0 -> bf16.
// ---------------------------------------------------------------------------
__global__ void detect_kernel(const void* x, int* flag) {
    const unsigned short* u = (const unsigned short*)x;
    int t = threadIdx.x;  // 64 threads
    int cnt = 0;
#pragma unroll
    for (int s = 0; s < 64; ++s) {
        unsigned short v = u[2 * (t * 64 + s)];
        int e = (v >> 7) & 0xFF;
        cnt += (e >= 0x8A || (e != 0 && e <= 0x6E)) ? 1 : 0;
    }
#pragma unroll
    for (int m = 1; m < 64; m <<= 1) cnt += __shfl_xor(cnt, m);
    if (t == 0) *flag = (cnt > 1024) ? 1 : 0;
}

// ---------------------------------------------------------------------------
// Convert the four 1024x1024 weights to canonical bf16.
// ---------------------------------------------------------------------------
__global__ __launch_bounds__(256) void cvt_w4_kernel(
    const void* Wq, const void* Wk, const void* Wv, const void* Wout,
    unsigned short* dq, unsigned short* dk, unsigned short* dv, unsigned short* dout,
    const int* flagp) {
    const bool isf = (*flagp != 0);
    const void* s;
    unsigned short* d;
    switch (blockIdx.y) {
        case 0: s = Wq; d = dq; break;
        case 1: s = Wk; d = dk; break;
        case 2: s = Wv; d = dv; break;
        default: s = Wout; d = dout; break;
    }
    size_t i = ((size_t)blockIdx.x * 256 + threadIdx.x) * 4;
#pragma unroll
    for (int r = 0; r < 4; ++r) d[i + r] = f2us(loadAny(s, i + r, isf));
}

// ---------------------------------------------------------------------------
// Convert gate weights (3 x 8x1024 -> bf16) and biases (-> f32).
// ---------------------------------------------------------------------------
__global__ __launch_bounds__(256) void cvt_small_kernel(
    const void* Wbeta, const void* Wig, const void* Wog,
    const void* bbeta, const void* big, const void* bog, const void* bout,
    unsigned short* dWb, unsigned short* dWi, unsigned short* dWo,
    float* dbb, float* dbi, float* dbo, float* dbout,
    const int* flagp) {
    const bool isf = (*flagp != 0);
    int gid = blockIdx.x * 256 + threadIdx.x;
    if (gid < 24576) {
        int seg = gid >> 13, off = gid & 8191;
        const void* s = (seg == 0) ? Wbeta : (seg == 1) ? Wig : Wog;
        unsigned short* d = (seg == 0) ? dWb : (seg == 1) ? dWi : dWo;
        d[off] = f2us(loadAny(s, off, isf));
    } else {
        int j = gid - 24576;
        if (j < 8) dbb[j] = loadAny(bbeta, j, isf);
        else if (j < 16) dbi[j - 8] = loadAny(big, j - 8, isf);
        else if (j < 24) dbo[j - 16] = loadAny(bog, j - 16, isf);
        else if (j < 24 + 1024) dbout[j - 24] = loadAny(bout, j - 24, isf);
    }
}

// ---------------------------------------------------------------------------
// RoPE tables: cos/sin[l][i], i < 64
// ---------------------------------------------------------------------------
__global__ __launch_bounds__(256) void rope_tables_kernel(float* __restrict__ cosT,
                                                          float* __restrict__ sinT) {
    int idx = blockIdx.x * 256 + threadIdx.x;
    int l = idx >> 6, i = idx & 63;
    float invf = powf(10000.0f, -(float)i * (1.0f / 64.0f));
    float fr = (float)l * invf;
    cosT[idx] = cosf(fr);
    sinT[idx] = sinf(fr);
}

// ---------------------------------------------------------------------------
// RMSNorm (dual-dtype input): h = x * rsqrt(mean(x^2)+1e-6) * w, h bf16.
// ---------------------------------------------------------------------------
__global__ __launch_bounds__(256) void rmsnorm_kernel(const void* __restrict__ xin,
                                                      const void* __restrict__ win,
                                                      __hip_bfloat16* __restrict__ h,
                                                      const int* __restrict__ flagp) {
    const bool isf = (*flagp != 0);
    const int row = blockIdx.x;
    const int tid = threadIdx.x;
    const int lane = tid & 63, wave = tid >> 6;
    const size_t base = (size_t)row * HID;
    float x0, x1, x2, x3;
    if (isf) {
        float4 u = ((const float4*)((const float*)xin + base))[tid];
        x0 = u.x; x1 = u.y; x2 = u.z; x3 = u.w;
    } else {
        ushort4 u = ((const ushort4*)((const unsigned short*)xin + base))[tid];
        x0 = bf2f(u.x); x1 = bf2f(u.y); x2 = bf2f(u.z); x3 = bf2f(u.w);
    }
    float ss = x0 * x0 + x1 * x1 + x2 * x2 + x3 * x3;
#pragma unroll
    for (int m = 1; m < 64; m <<= 1) ss += __shfl_xor(ss, m);
    __shared__ float wsum[4];
    if (lane == 0) wsum[wave] = ss;
    __syncthreads();
    float tot = wsum[0] + wsum[1] + wsum[2] + wsum[3];
    float inv = rsqrtf(tot * (1.0f / HID) + 1e-6f);
    float w0, w1, w2, w3;
    if (isf) {
        float4 u = ((const float4*)win)[tid];
        w0 = u.x; w1 = u.y; w2 = u.z; w3 = u.w;
    } else {
        ushort4 u = ((const ushort4*)win)[tid];
        w0 = bf2f(u.x); w1 = bf2f(u.y); w2 = bf2f(u.z); w3 = bf2f(u.w);
    }
    __hip_bfloat16* ho = h + base + tid * 4;
    ho[0] = __float2bfloat16(x0 * inv * w0);
    ho[1] = __float2bfloat16(x1 * inv * w1);
    ho[2] = __float2bfloat16(x2 * inv * w2);
    ho[3] = __float2bfloat16(x3 * inv * w3);
}

// ---------------------------------------------------------------------------
// Gates: sigmoid(h . Wg[hh] + bias), output [bh][L] f32.
// ---------------------------------------------------------------------------
__global__ __launch_bounds__(256) void gates_kernel(
    const __hip_bfloat16* __restrict__ h,
    const __hip_bfloat16* __restrict__ Wbeta, const float* __restrict__ bbeta,
    const __hip_bfloat16* __restrict__ Wig, const float* __restrict__ big,
    const __hip_bfloat16* __restrict__ Wog, const float* __restrict__ bog,
    float* __restrict__ fT, float* __restrict__ gT, float* __restrict__ oT) {
    const int row = blockIdx.x;
    const int tid = threadIdx.x;
    const int lane = tid & 63, wave = tid >> 6;
    const int b = row >> 12, l = row & (LQ - 1);
    const unsigned short* hp = (const unsigned short*)h + (size_t)row * HID + tid * 4;
    ushort4 hu = *(const ushort4*)hp;
    float h0 = bf2f(hu.x), h1 = bf2f(hu.y), h2 = bf2f(hu.z), h3 = bf2f(hu.w);
    float p[24];
#pragma unroll
    for (int g = 0; g < 24; ++g) {
        const __hip_bfloat16* wr = (g < 8) ? (Wbeta + g * HID)
                                 : (g < 16) ? (Wig + (g - 8) * HID)
                                            : (Wog + (g - 16) * HID);
        const unsigned short* wp = (const unsigned short*)wr + tid * 4;
        ushort4 wu = *(const ushort4*)wp;
        p[g] = h0 * bf2f(wu.x) + h1 * bf2f(wu.y) + h2 * bf2f(wu.z) + h3 * bf2f(wu.w);
    }
#pragma unroll
    for (int m = 1; m < 64; m <<= 1) {
#pragma unroll
        for (int g = 0; g < 24; ++g) p[g] += __shfl_xor(p[g], m);
    }
    __shared__ float part[4][24];
    if (lane == 0) {
#pragma unroll
        for (int g = 0; g < 24; ++g) part[wave][g] = p[g];
    }
    __syncthreads();
    if (tid < 24) {
        int g = tid;
        float s = part[0][g] + part[1][g] + part[2][g] + part[3][g];
        float bb = (g < 8) ? bbeta[g] : (g < 16) ? big[g - 8] : bog[g - 16];
        s += bb;
        s = 1.0f / (1.0f + expf(-s));
        int hh = (g < 8) ? g : (g < 16) ? g - 8 : g - 16;
        float* dst = (g < 8) ? fT : (g < 16) ? gT : oT;
        dst[((size_t)(b * NHEAD + hh)) * LQ + l] = s;
    }
}

// ---------------------------------------------------------------------------
// Merged QKV GEMM: one dispatch, blockIdx.y selects {Wq,Wk,Wv} and {qb,kb,vb}.
// ---------------------------------------------------------------------------
__global__ __launch_bounds__(256) void gemm_qkv(const __hip_bfloat16* __restrict__ A,
                                                const unsigned short* __restrict__ Wqc,
                                                const unsigned short* __restrict__ Wkc,
                                                const unsigned short* __restrict__ Wvc,
                                                unsigned short* __restrict__ qb,
                                                unsigned short* __restrict__ kb,
                                                unsigned short* __restrict__ vb) {
    __shared__ unsigned short As[128 * 32];
    __shared__ unsigned short Bs[128 * 32];
    const int sel = blockIdx.y >> 3;
    const __hip_bfloat16* W = (const __hip_bfloat16*)(sel == 0 ? Wqc : sel == 1 ? Wkc : Wvc);
    unsigned short* C = (sel == 0) ? qb : (sel == 1) ? kb : vb;
    const int tid = threadIdx.x;
    const int lane = tid & 63, wave = tid >> 6;
    const int m0 = blockIdx.x * 128, n0 = (blockIdx.y & 7) * 128;
    const int wm = (wave & 1) * 64, wn = (wave >> 1) * 64;
    const int lm = lane & 15, lq = lane >> 4;
    f32x4 acc[4][4] = {};
    const int c0 = tid, c1 = tid + 256;
    const int r0 = c0 >> 2, o0 = (c0 & 3) * 8;
    const int r1 = c1 >> 2, o1 = (c1 & 3) * 8;
    for (int k0 = 0; k0 < HID; k0 += 32) {
        __builtin_amdgcn_global_load_lds(
            (const __attribute__((address_space(1))) void*)(A + (size_t)(m0 + r0) * HID + k0 + o0),
            (__attribute__((address_space(3))) void*)(As + c0 * 8), 16, 0, 0);
        __builtin_amdgcn_global_load_lds(
            (const __attribute__((address_space(1))) void*)(A + (size_t)(m0 + r1) * HID + k0 + o1),
            (__attribute__((address_space(3))) void*)(As + c1 * 8), 16, 0, 0);
        __builtin_amdgcn_global_load_lds(
            (const __attribute__((address_space(1))) void*)(W + (size_t)(n0 + r0) * HID + k0 + o0),
            (__attribute__((address_space(3))) void*)(Bs + c0 * 8), 16, 0, 0);
        __builtin_amdgcn_global_load_lds(
            (const __attribute__((address_space(1))) void*)(W + (size_t)(n0 + r1) * HID + k0 + o1),
            (__attribute__((address_space(3))) void*)(Bs + c1 * 8), 16, 0, 0);
        __syncthreads();
        bf16x8 af[4], bfr[4];
#pragma unroll
        for (int i = 0; i < 4; ++i)
            af[i] = *(const bf16x8*)(const void*)(As + (wm + i * 16 + lm) * 32 + lq * 8);
#pragma unroll
        for (int j = 0; j < 4; ++j)
            bfr[j] = *(const bf16x8*)(const void*)(Bs + (wn + j * 16 + lm) * 32 + lq * 8);
#pragma unroll
        for (int i = 0; i < 4; ++i)
#pragma unroll
            for (int j = 0; j < 4; ++j)
                acc[i][j] = __builtin_amdgcn_mfma_f32_16x16x32_bf16(af[i], bfr[j], acc[i][j], 0, 0, 0);
        __syncthreads();
    }
#pragma unroll
    for (int i = 0; i < 4; ++i)
#pragma unroll
        for (int j = 0; j < 4; ++j) {
            int col = n0 + wn + j * 16 + lm;
#pragma unroll
            for (int r = 0; r < 4; ++r) {
                int rowg = m0 + wm + i * 16 + lq * 4 + r;
                C[(size_t)rowg * HID + col] = f2us(acc[i][j][r]);
            }
        }
}

// ---------------------------------------------------------------------------
// Final GEMM (m97): C = A W^T + bias; C f32 when (*flagp), else bf16.
// ---------------------------------------------------------------------------
__global__ __launch_bounds__(256) void gemm_bt(const __hip_bfloat16* __restrict__ A,
                                               const __hip_bfloat16* __restrict__ W,
                                               const float* __restrict__ bias,
                                               void* __restrict__ C,
                                               const int* __restrict__ flagp) {
    __shared__ unsigned short As[128 * 32];
    __shared__ unsigned short Bs[128 * 32];
    const bool f32out = (*flagp != 0);
    const int tid = threadIdx.x;
    const int lane = tid & 63, wave = tid >> 6;
    const int m0 = blockIdx.x * 128, n0 = blockIdx.y * 128;
    const int wm = (wave & 1) * 64, wn = (wave >> 1) * 64;
    const int lm = lane & 15, lq = lane >> 4;
    f32x4 acc[4][4] = {};
    const int c0 = tid, c1 = tid + 256;
    const int r0 = c0 >> 2, o0 = (c0 & 3) * 8;
    const int r1 = c1 >> 2, o1 = (c1 & 3) * 8;
    for (int k0 = 0; k0 < HID; k0 += 32) {
        __builtin_amdgcn_global_load_lds(
            (const __attribute__((address_space(1))) void*)(A + (size_t)(m0 + r0) * HID + k0 + o0),
            (__attribute__((address_space(3))) void*)(As + c0 * 8), 16, 0, 0);
        __builtin_amdgcn_global_load_lds(
            (const __attribute__((address_space(1))) void*)(A + (size_t)(m0 + r1) * HID + k0 + o1),
            (__attribute__((address_space(3))) void*)(As + c1 * 8), 16, 0, 0);
        __builtin_amdgcn_global_load_lds(
            (const __attribute__((address_space(1))) void*)(W + (size_t)(n0 + r0) * HID + k0 + o0),
            (__attribute__((address_space(3))) void*)(Bs + c0 * 8), 16, 0, 0);
        __builtin_amdgcn_global_load_lds(
            (const __attribute__((address_space(1))) void*)(W + (size_t)(n0 + r1) * HID + k0 + o1),
            (__attribute__((address_space(3))) void*)(Bs + c1 * 8), 16, 0, 0);
        __syncthreads();
        bf16x8 af[4], bfr[4];
#pragma unroll
        for (int i = 0; i < 4; ++i)
            af[i] = *(const bf16x8*)(const void*)(As + (wm + i * 16 + lm) * 32 + lq * 8);
#pragma unroll
        for (int j = 0; j < 4; ++j)
            bfr[j] = *(const bf16x8*)(const void*)(Bs + (wn + j * 16 + lm) * 32 + lq * 8);
#pragma unroll
        for (int i = 0; i < 4; ++i)
#pragma unroll
            for (int j = 0; j < 4; ++j)
                acc[i][j] = __builtin_amdgcn_mfma_f32_16x16x32_bf16(af[i], bfr[j], acc[i][j], 0, 0, 0);
        __syncthreads();
    }
#pragma unroll
    for (int i = 0; i < 4; ++i)
#pragma unroll
        for (int j = 0; j < 4; ++j) {
            int col = n0 + wn + j * 16 + lm;
            float bv = bias[col];
#pragma unroll
            for (int r = 0; r < 4; ++r) {
                int rowg = m0 + wm + i * 16 + lq * 4 + r;
                size_t idx = (size_t)rowg * HID + col;
                float val = acc[i][j][r] + bv;
                if (f32out) ((float*)C)[idx] = val;
                else ((__hip_bfloat16*)C)[idx] = __float2bfloat16(val);
            }
        }
}

// ---------------------------------------------------------------------------
// INTRA kernel + prep for inter. Per (chunk, bh) block:
//  - causal within-chunk Y_intra via MFMA -> yb = o*Y_intra
//  - PREP: qb <- exp(Lp_j)*rope(q) in place (rows owned exclusively);
//          KtG[bh][chunk] <- w2_s*rope(k), pre-transposed LDS-ready
//          layout [ks(2)][d(128)][32 s-shorts]; cdecG[bh][chunk] = exp(Lp_63).
// ---------------------------------------------------------------------------
__global__ __launch_bounds__(256) void intra_kernel(
    unsigned short* __restrict__ qg, const unsigned short* __restrict__ kg,
    const unsigned short* __restrict__ vg,
    const float* __restrict__ fT, const float* __restrict__ gT, const float* __restrict__ oT,
    const float* __restrict__ cosT, const float* __restrict__ sinT,
    __hip_bfloat16* __restrict__ yb,
    unsigned short* __restrict__ ktg, float* __restrict__ cdecG) {
    const int chunk = blockIdx.x;        // 0..63
    const int bh = blockIdx.y;           // 0..31
    const int b = bh >> 3, hh = bh & 7;
    const int t0 = chunk * CCH;
    const int tid = threadIdx.x;
    const int lane = tid & 63, wave = tid >> 6;
    const int lm = lane & 15, lq = lane >> 4;
    __shared__ unsigned short Qr[64 * 136];
    __shared__ unsigned short Kr[64 * 136];
    __shared__ unsigned short Vt[128 * 72];
    __shared__ unsigned short Sp[64 * 72];
    __shared__ float Lp[64], aS[64], osh[64], w2s[64], qscs[64];

    // phase 0: gates + decay prefix (wave 0)
    if (tid < 64) {
        float f = fT[(size_t)bh * LQ + t0 + tid];
        float g = gT[(size_t)bh * LQ + t0 + tid];
        osh[tid] = oT[(size_t)bh * LQ + t0 + tid];
        float lf = __logf(f);
#pragma unroll
        for (int off = 1; off < 64; off <<= 1) {
            float v = __shfl_up(lf, off);
            if (lane >= off) lf += v;
        }
        float tot = __shfl(lf, 63);
        Lp[tid] = lf;
        aS[tid] = g * 0.08838834764831845f;  // g / sqrt(128)
        w2s[tid] = __expf(tot - lf) * (g * 0.08838834764831845f);
        qscs[tid] = __expf(lf);
        if (tid == 63) cdecG[bh * NCH + chunk] = __expf(lf);
    }
    __syncthreads();  // B0: qscs ready for staging write-back

    // phase 1: rope-stage q,k (raw, LDS) + write qb back scaled (in place)
#pragma unroll
    for (int r = 0; r < 16; ++r) {
        int pid = r * 256 + tid;
        int t = pid >> 6, i = pid & 63;
        int gt = t0 + t;
        size_t gidx = ((size_t)(b * LQ + gt)) * HID + hh * DHEAD + i;
        float c = cosT[gt * 64 + i], s = sinT[gt * 64 + i];
        float q1 = bf2f(qg[gidx]), q2 = bf2f(qg[gidx + 64]);
        float qa = q1 * c - q2 * s, qb2 = q1 * s + q2 * c;
        Qr[t * 136 + i] = f2us(qa);
        Qr[t * 136 + i + 64] = f2us(qb2);
        float sc = qscs[t];
        qg[gidx] = f2us(qa * sc);
        qg[gidx + 64] = f2us(qb2 * sc);
        float k1 = bf2f(kg[gidx]), k2 = bf2f(kg[gidx + 64]);
        Kr[t * 136 + i] = f2us(k1 * c - k2 * s);
        Kr[t * 136 + i + 64] = f2us(k1 * s + k2 * c);
    }
    // stage V transposed: Vt[e][s]
#pragma unroll
    for (int r = 0; r < 32; ++r) {
        int lin = r * 256 + tid;
        int sI = lin >> 7, e = lin & 127;
        float val = bf2f(vg[((size_t)(b * LQ + t0 + sI)) * HID + hh * DHEAD + e]);
        Vt[e * 72 + sI] = f2us(val);
    }
    __syncthreads();  // B1

    // S = Q K^T (64x64, K=128); wave handles j-strip [16*wave, +16)
    f32x4 sacc[4] = {};
#pragma unroll
    for (int ks = 0; ks < 4; ++ks) {
        bf16x8 af = *(const bf16x8*)(const void*)(Qr + (16 * wave + lm) * 136 + ks * 32 + lq * 8);
#pragma unroll
        for (int nt = 0; nt < 4; ++nt) {
            bf16x8 bf = *(const bf16x8*)(const void*)(Kr + (nt * 16 + lm) * 136 + ks * 32 + lq * 8);
            sacc[nt] = __builtin_amdgcn_mfma_f32_16x16x32_bf16(af, bf, sacc[nt], 0, 0, 0);
        }
    }
    // mask + decay/gate scale, store S' bf16 [j][s]
#pragma unroll
    for (int nt = 0; nt < 4; ++nt) {
#pragma unroll
        for (int r = 0; r < 4; ++r) {
            int j = 16 * wave + lq * 4 + r;
            int s = nt * 16 + lm;
            float v = 0.0f;
            if (j >= s) v = sacc[nt][r] * __expf(Lp[j] - Lp[s]) * aS[s];
            Sp[j * 72 + s] = f2us(v);
        }
    }
    // PREP: KtG[ks][d][32] = w2_s * Kr[s][d]  (transpose out of LDS, coalesced write)
    {
        unsigned short* krec = ktg + ((size_t)(bh * NCH + chunk)) * 8192;
#pragma unroll
        for (int r = 0; r < 2; ++r) {
            int lin16 = r * 256 + tid;          // 0..511, 16 shorts each
            int ks = lin16 >> 8;
            int d = (lin16 & 255) >> 1;
            int cc0 = (lin16 & 1) * 16;
            __align__(16) unsigned short out[16];
#pragma unroll
            for (int u = 0; u < 16; ++u) {
                int s = ks * 32 + cc0 + u;
                out[u] = f2us(w2s[s] * bf2f(Kr[s * 136 + d]));
            }
            uint4* dst = (uint4*)(krec + (size_t)lin16 * 16);
            dst[0] = *(const uint4*)(out);
            dst[1] = *(const uint4*)(out + 8);
        }
    }
    __syncthreads();  // B2

    // Y_intra = S' V  (64x128, K=64)
    f32x4 ya[8] = {};
#pragma unroll
    for (int ks = 0; ks < 2; ++ks) {
        bf16x8 af = *(const bf16x8*)(const void*)(Sp + (16 * wave + lm) * 72 + ks * 32 + lq * 8);
#pragma unroll
        for (int nt = 0; nt < 8; ++nt) {
            bf16x8 bf = *(const bf16x8*)(const void*)(Vt + (nt * 16 + lm) * 72 + ks * 32 + lq * 8);
            ya[nt] = __builtin_amdgcn_mfma_f32_16x16x32_bf16(af, bf, ya[nt], 0, 0, 0);
        }
    }
#pragma unroll
    for (int nt = 0; nt < 8; ++nt) {
#pragma unroll
        for (int r = 0; r < 4; ++r) {
            int j = 16 * wave + lq * 4 + r;
            int e = nt * 16 + lm;
            size_t row = (size_t)(b * LQ + t0 + j);
            yb[row * HID + hh * DHEAD + e] = __float2bfloat16(osh[j] * ya[nt][r]);
        }
    }
}

// ---------------------------------------------------------------------------
// INTER kernel: sequential over 64 chunks, double-buffered global_load_lds
// prefetch. Block (bh, esplit) owns M[16 e][128 d] f32 in LDS.
// LDS sizes: Qsl [ks(4)][j(64)][32] = 8192 shorts/buf (16 KB),
//            Ktl [ks(2)][d(128)][32] = 8192 shorts/buf,
//            Vtl [ks(2)][e(16)][32] = 1024 shorts/buf.
// ---------------------------------------------------------------------------
__global__ __launch_bounds__(256) void inter_kernel(
    const unsigned short* __restrict__ qs,   // exp(Lp_j)*rope(q), [row][128]
    const unsigned short* __restrict__ ktg,  // [bh][chunk][ks][d][32]
    const unsigned short* __restrict__ vg,
    const float* __restrict__ oT, const float* __restrict__ cdecG,
    unsigned short* __restrict__ yb) {
    const int bh = blockIdx.x;       // 0..31
    const int esplit = blockIdx.y;   // 0..7
    const int e0 = esplit * 16;
    const int b = bh >> 3, hh = bh & 7;
    const int tid = threadIdx.x;
    const int lane = tid & 63, wave = tid >> 6;
    const int lm = lane & 15, lq = lane >> 4;
    __shared__ __align__(16) unsigned short Qsl[2][8192];  // [ks(4)][j(64)][32]
    __shared__ __align__(16) unsigned short Ktl[2][8192];  // [ks(2)][d(128)][32]
    __shared__ __align__(16) unsigned short Vtl[2][2048];  // [ks(2)][e(16)][32]
    __shared__ __align__(16) float Ml[16 * 132];           // M^T [e][d], stride 132

    for (int i = tid; i < 16 * 132; i += 256) Ml[i] = 0.0f;

    const int jrow = tid >> 2;               // Q gather: row within chunk
    const int qcol = (tid & 3) * 8;
    for (int c = -1; c < NCH; ++c) {
        // ---- prefetch / prologue staging for chunk c+1 ----
        if (c + 1 < NCH) {
            const int nbuf = (c + 1) & 1;
            const int t0n = (c + 1) * CCH;
            const unsigned short* qrow =
                qs + ((size_t)(b * LQ + t0n + jrow)) * HID + hh * DHEAD + qcol;
#pragma unroll
            for (int ks = 0; ks < 4; ++ks)
                __builtin_amdgcn_global_load_lds(
                    (const __attribute__((address_space(1))) void*)(qrow + ks * 32),
                    (__attribute__((address_space(3))) void*)(&Qsl[nbuf][ks * 2048 + tid * 8]),
                    16, 0, 0);
            const unsigned short* kbase = ktg + ((size_t)(bh * NCH + c + 1)) * 8192 + tid * 8;
#pragma unroll
            for (int i = 0; i < 4; ++i)
                __builtin_amdgcn_global_load_lds(
                    (const __attribute__((address_space(1))) void*)(kbase + i * 2048),
                    (__attribute__((address_space(3))) void*)(&Ktl[nbuf][i * 2048 + tid * 8]),
                    16, 0, 0);
        }
        if (c < 0) {
            // prologue V stage for chunk 0
#pragma unroll
            for (int r = 0; r < 4; ++r) {
                int lin = r * 256 + tid;
                int s = lin >> 4, e = lin & 15;
                float val = bf2f(vg[((size_t)(b * LQ + s)) * HID + hh * DHEAD + e0 + e]);
                Vtl[0][(s >> 5) * 512 + e * 32 + (s & 31)] = f2us(val);
            }
            continue;
        }
        const int cur = c & 1, nxt = cur ^ 1;
        const int t0 = c * CCH;
        const float cd = cdecG[bh * NCH + c];
        __syncthreads();  // (A): chunk-c LDS data arrived (vmcnt drained), Ml stable
        // U = K''^T V : wave d-strip [32*wave, +32)
        f32x4 uacc[2] = {};
#pragma unroll
        for (int ks = 0; ks < 2; ++ks) {
            bf16x8 bfv = *(const bf16x8*)(const void*)(&Vtl[cur][ks * 512 + lm * 32 + lq * 8]);
#pragma unroll
            for (int mt = 0; mt < 2; ++mt) {
                bf16x8 af = *(const bf16x8*)(const void*)(
                    &Ktl[cur][ks * 4096 + (32 * wave + 16 * mt + lm) * 32 + lq * 8]);
                uacc[mt] = __builtin_amdgcn_mfma_f32_16x16x32_bf16(af, bfv, uacc[mt], 0, 0, 0);
            }
        }
        // Y = Qs @ M : wave j-strip [16*wave, +16)
        f32x4 yacc = {};
#pragma unroll
        for (int ks = 0; ks < 4; ++ks) {
            bf16x8 af = *(const bf16x8*)(const void*)(
                &Qsl[cur][ks * 2048 + (16 * wave + lm) * 32 + lq * 8]);
            float4 m0 = *(const float4*)(const void*)(Ml + lm * 132 + ks * 32 + lq * 8);
            float4 m1 = *(const float4*)(const void*)(Ml + lm * 132 + ks * 32 + lq * 8 + 4);
            __align__(16) unsigned short tmp[8];
            tmp[0] = f2us(m0.x); tmp[1] = f2us(m0.y); tmp[2] = f2us(m0.z); tmp[3] = f2us(m0.w);
            tmp[4] = f2us(m1.x); tmp[5] = f2us(m1.y); tmp[6] = f2us(m1.z); tmp[7] = f2us(m1.w);
            bf16x8 bfm = *(const bf16x8*)tmp;
            yacc = __builtin_amdgcn_mfma_f32_16x16x32_bf16(af, bfm, yacc, 0, 0, 0);
        }
        // yb += o * Y_inter
#pragma unroll
        for (int r = 0; r < 4; ++r) {
            int j = 16 * wave + lq * 4 + r;
            float o = oT[(size_t)bh * LQ + t0 + j];
            size_t idx = ((size_t)(b * LQ + t0 + j)) * HID + hh * DHEAD + e0 + lm;
            yb[idx] = f2us(bf2f(yb[idx]) + o * yacc[r]);
        }
        // VALU-stage V for chunk c+1 into nxt
        if (c + 1 < NCH) {
            const int t0n = (c + 1) * CCH;
#pragma unroll
            for (int r = 0; r < 4; ++r) {
                int lin = r * 256 + tid;
                int s = lin >> 4, e = lin & 15;
                float val = bf2f(vg[((size_t)(b * LQ + t0n + s)) * HID + hh * DHEAD + e0 + e]);
                Vtl[nxt][(s >> 5) * 512 + e * 32 + (s & 31)] = f2us(val);
            }
        }
        __syncthreads();  // (B): all Ml reads done
        // M = cdec*M + U
#pragma unroll
        for (int mt = 0; mt < 2; ++mt)
#pragma unroll
            for (int r = 0; r < 4; ++r) {
                int d = 32 * wave + 16 * mt + lq * 4 + r;
                Ml[lm * 132 + d] = cd * Ml[lm * 132 + d] + uacc[mt][r];
            }
    }
}

// ---------------------------------------------------------------------------
extern "C" void kernel_launch(void* const* d_in, const int* in_sizes, int n_in,
                              void* d_out, int out_size, void* d_ws, size_t ws_size,
                              hipStream_t stream) {
    const void* x      = d_in[0];
    const void* norm_w = d_in[1];
    const void* Wq     = d_in[2];
    const void* Wk     = d_in[3];
    const void* Wv     = d_in[4];
    const void* Wbeta  = d_in[5];
    const void* bbeta  = d_in[6];
    const void* Wig    = d_in[7];
    const void* big    = d_in[8];
    const void* Wog    = d_in[9];
    const void* bog    = d_in[10];
    const void* Wout   = d_in[11];
    const void* bout   = d_in[12];

    char* ws = (char*)d_ws;
    const size_t KB = 1024, MB = 1024 * 1024;
    int*   flag    = (int*)(ws + 0);
    float* bbeta_c = (float*)(ws + 1 * KB);
    float* big_c   = (float*)(ws + 1 * KB + 32);
    float* bog_c   = (float*)(ws + 1 * KB + 64);
    float* bout_c  = (float*)(ws + 4 * KB);
    float* cdecG   = (float*)(ws + 16 * KB);            // 8 KiB
    unsigned short* Wbeta_c = (unsigned short*)(ws + 64 * KB);
    unsigned short* Wig_c   = (unsigned short*)(ws + 96 * KB);
    unsigned short* Wog_c   = (unsigned short*)(ws + 128 * KB);
    float* fT   = (float*)(ws + 1 * MB);
    float* gT   = (float*)(ws + 1 * MB + 512 * KB);
    float* oT   = (float*)(ws + 2 * MB);
    float* cosT = (float*)(ws + 2 * MB + 512 * KB);
    float* sinT = (float*)(ws + 3 * MB + 512 * KB);
    unsigned short* Wq_c   = (unsigned short*)(ws + 5 * MB);
    unsigned short* Wk_c   = (unsigned short*)(ws + 7 * MB);
    unsigned short* Wv_c   = (unsigned short*)(ws + 9 * MB);
    unsigned short* Wout_c = (unsigned short*)(ws + 11 * MB);
    __hip_bfloat16* h  = (__hip_bfloat16*)(ws + 16 * MB);   // 32 MiB; dead after QKV gemm
    unsigned short* ktg = (unsigned short*)(ws + 16 * MB);  // aliases h (32 MiB)
    unsigned short* qb = (unsigned short*)(ws + 48 * MB);
    unsigned short* kb = (unsigned short*)(ws + 80 * MB);
    unsigned short* vb = (unsigned short*)(ws + 112 * MB);
    __hip_bfloat16* yb = (__hip_bfloat16*)(ws + 144 * MB);

    detect_kernel<<<1, 64, 0, stream>>>(x, flag);
    cvt_w4_kernel<<<dim3(1024, 4), 256, 0, stream>>>(Wq, Wk, Wv, Wout,
                                                     Wq_c, Wk_c, Wv_c, Wout_c, flag);
    cvt_small_kernel<<<101, 256, 0, stream>>>(Wbeta, Wig, Wog, bbeta, big, bog, bout,
                                              Wbeta_c, Wig_c, Wog_c,
                                              bbeta_c, big_c, bog_c, bout_c, flag);
    rope_tables_kernel<<<(LQ * 64) / 256, 256, 0, stream>>>(cosT, sinT);
    rmsnorm_kernel<<<MROWS, 256, 0, stream>>>(x, norm_w, h, flag);
    gates_kernel<<<MROWS, 256, 0, stream>>>(h, (const __hip_bfloat16*)Wbeta_c, bbeta_c,
                                            (const __hip_bfloat16*)Wig_c, big_c,
                                            (const __hip_bfloat16*)Wog_c, bog_c, fT, gT, oT);

    gemm_qkv<<<dim3(MROWS / 128, 24), 256, 0, stream>>>(h, Wq_c, Wk_c, Wv_c, qb, kb, vb);

    intra_kernel<<<dim3(NCH, 32), 256, 0, stream>>>(qb, kb, vb, fT, gT, oT, cosT, sinT,
                                                    (__hip_bfloat16*)yb, ktg, cdecG);
    inter_kernel<<<dim3(32, 8), 256, 0, stream>>>(qb, ktg, vb, oT, cdecG,
                                                  (unsigned short*)yb);

    gemm_bt<<<dim3(MROWS / 128, HID / 128), 256, 0, stream>>>(
        (const __hip_bfloat16*)yb, (const __hip_bfloat16*)Wout_c, bout_c, d_out, flag);
}

// Round 6
// 543.387 us; speedup vs baseline: 2.9271x; 1.1222x over previous
//
#include <hip/hip_runtime.h>
#include <hip/hip_bf16.h>

#define BQ 4
#define LQ 4096
#define HID 1024
#define NHEAD 8
#define DHEAD 128
#define MROWS (BQ * LQ) /* 16384 */
#define CCH 64          /* chunk length */
#define NCH (LQ / CCH)  /* 64 chunks */

typedef __bf16 bf16x8 __attribute__((ext_vector_type(8)));
typedef float f32x4 __attribute__((ext_vector_type(4)));

__device__ __forceinline__ float bf2f(unsigned short u) {
    return __uint_as_float(((unsigned int)u) << 16);
}
__device__ __forceinline__ unsigned short f2us(float f) {
    __hip_bfloat16 b = __float2bfloat16(f);
    return *reinterpret_cast<unsigned short*>(&b);
}
__device__ __forceinline__ float loadAny(const void* p, size_t i, bool isf) {
    return isf ? ((const float*)p)[i] : bf2f(((const unsigned short*)p)[i]);
}

// ---------------------------------------------------------------------------
// Dtype probe: flag=1 -> inputs are f32; flag=0 -> bf16.
// ---------------------------------------------------------------------------
__global__ void detect_kernel(const void* x, int* flag) {
    const unsigned short* u = (const unsigned short*)x;
    int t = threadIdx.x;  // 64 threads
    int cnt = 0;
#pragma unroll
    for (int s = 0; s < 64; ++s) {
        unsigned short v = u[2 * (t * 64 + s)];
        int e = (v >> 7) & 0xFF;
        cnt += (e >= 0x8A || (e != 0 && e <= 0x6E)) ? 1 : 0;
    }
#pragma unroll
    for (int m = 1; m < 64; m <<= 1) cnt += __shfl_xor(cnt, m);
    if (t == 0) *flag = (cnt > 1024) ? 1 : 0;
}

// ---------------------------------------------------------------------------
// Convert the four 1024x1024 weights to bf16; blockIdx.y==4 builds RoPE tables.
// ---------------------------------------------------------------------------
__global__ __launch_bounds__(256) void cvt_w4_kernel(
    const void* Wq, const void* Wk, const void* Wv, const void* Wout,
    unsigned short* dq, unsigned short* dk, unsigned short* dv, unsigned short* dout,
    float* __restrict__ cosT, float* __restrict__ sinT,
    const int* flagp) {
    if (blockIdx.y == 4) {
        int idx = blockIdx.x * 256 + threadIdx.x;  // 0..262143 = 4096*64
        int l = idx >> 6, i = idx & 63;
        float invf = powf(10000.0f, -(float)i * (1.0f / 64.0f));
        float fr = (float)l * invf;
        cosT[idx] = cosf(fr);
        sinT[idx] = sinf(fr);
        return;
    }
    const bool isf = (*flagp != 0);
    const void* s;
    unsigned short* d;
    switch (blockIdx.y) {
        case 0: s = Wq; d = dq; break;
        case 1: s = Wk; d = dk; break;
        case 2: s = Wv; d = dv; break;
        default: s = Wout; d = dout; break;
    }
    size_t i = ((size_t)blockIdx.x * 256 + threadIdx.x) * 4;
#pragma unroll
    for (int r = 0; r < 4; ++r) d[i + r] = f2us(loadAny(s, i + r, isf));
}

// ---------------------------------------------------------------------------
// Convert gate weights (3 x 8x1024 -> bf16) and biases (-> f32).
// ---------------------------------------------------------------------------
__global__ __launch_bounds__(256) void cvt_small_kernel(
    const void* Wbeta, const void* Wig, const void* Wog,
    const void* bbeta, const void* big, const void* bog, const void* bout,
    unsigned short* dWb, unsigned short* dWi, unsigned short* dWo,
    float* dbb, float* dbi, float* dbo, float* dbout,
    const int* flagp) {
    const bool isf = (*flagp != 0);
    int gid = blockIdx.x * 256 + threadIdx.x;
    if (gid < 24576) {
        int seg = gid >> 13, off = gid & 8191;
        const void* s = (seg == 0) ? Wbeta : (seg == 1) ? Wig : Wog;
        unsigned short* d = (seg == 0) ? dWb : (seg == 1) ? dWi : dWo;
        d[off] = f2us(loadAny(s, off, isf));
    } else {
        int j = gid - 24576;
        if (j < 8) dbb[j] = loadAny(bbeta, j, isf);
        else if (j < 16) dbi[j - 8] = loadAny(big, j - 8, isf);
        else if (j < 24) dbo[j - 16] = loadAny(bog, j - 16, isf);
        else if (j < 24 + 1024) dbout[j - 24] = loadAny(bout, j - 24, isf);
    }
}

// ---------------------------------------------------------------------------
// Fused RMSNorm + gates: h = x*rsqrt(mean(x^2)+1e-6)*w (bf16 out), and the
// 24 sigmoid gates computed from the normalized row held in registers.
// One block per row; saves a full 32 MB re-read of h vs separate kernels.
// ---------------------------------------------------------------------------
__global__ __launch_bounds__(256) void rmsnorm_gates_kernel(
    const void* __restrict__ xin, const void* __restrict__ win,
    __hip_bfloat16* __restrict__ h, const int* __restrict__ flagp,
    const __hip_bfloat16* __restrict__ Wbeta, const float* __restrict__ bbeta,
    const __hip_bfloat16* __restrict__ Wig, const float* __restrict__ big,
    const __hip_bfloat16* __restrict__ Wog, const float* __restrict__ bog,
    float* __restrict__ fT, float* __restrict__ gT, float* __restrict__ oT) {
    const bool isf = (*flagp != 0);
    const int row = blockIdx.x;
    const int tid = threadIdx.x;
    const int lane = tid & 63, wave = tid >> 6;
    const int b = row >> 12, l = row & (LQ - 1);
    const size_t base = (size_t)row * HID;
    float x0, x1, x2, x3;
    if (isf) {
        float4 u = ((const float4*)((const float*)xin + base))[tid];
        x0 = u.x; x1 = u.y; x2 = u.z; x3 = u.w;
    } else {
        ushort4 u = ((const ushort4*)((const unsigned short*)xin + base))[tid];
        x0 = bf2f(u.x); x1 = bf2f(u.y); x2 = bf2f(u.z); x3 = bf2f(u.w);
    }
    float ss = x0 * x0 + x1 * x1 + x2 * x2 + x3 * x3;
#pragma unroll
    for (int m = 1; m < 64; m <<= 1) ss += __shfl_xor(ss, m);
    __shared__ float wsum[4];
    if (lane == 0) wsum[wave] = ss;
    __syncthreads();
    float tot = wsum[0] + wsum[1] + wsum[2] + wsum[3];
    float inv = rsqrtf(tot * (1.0f / HID) + 1e-6f);
    float w0, w1, w2, w3;
    if (isf) {
        float4 u = ((const float4*)win)[tid];
        w0 = u.x; w1 = u.y; w2 = u.z; w3 = u.w;
    } else {
        ushort4 u = ((const ushort4*)win)[tid];
        w0 = bf2f(u.x); w1 = bf2f(u.y); w2 = bf2f(u.z); w3 = bf2f(u.w);
    }
    float h0 = x0 * inv * w0, h1 = x1 * inv * w1, h2 = x2 * inv * w2, h3 = x3 * inv * w3;
    __hip_bfloat16* ho = h + base + tid * 4;
    ho[0] = __float2bfloat16(h0);
    ho[1] = __float2bfloat16(h1);
    ho[2] = __float2bfloat16(h2);
    ho[3] = __float2bfloat16(h3);
    // gates from register h
    float p[24];
#pragma unroll
    for (int g = 0; g < 24; ++g) {
        const __hip_bfloat16* wr = (g < 8) ? (Wbeta + g * HID)
                                 : (g < 16) ? (Wig + (g - 8) * HID)
                                            : (Wog + (g - 16) * HID);
        const unsigned short* wp = (const unsigned short*)wr + tid * 4;
        ushort4 wu = *(const ushort4*)wp;
        p[g] = h0 * bf2f(wu.x) + h1 * bf2f(wu.y) + h2 * bf2f(wu.z) + h3 * bf2f(wu.w);
    }
#pragma unroll
    for (int m = 1; m < 64; m <<= 1) {
#pragma unroll
        for (int g = 0; g < 24; ++g) p[g] += __shfl_xor(p[g], m);
    }
    __shared__ float part[4][24];
    if (lane == 0) {
#pragma unroll
        for (int g = 0; g < 24; ++g) part[wave][g] = p[g];
    }
    __syncthreads();
    if (tid < 24) {
        int g = tid;
        float s = part[0][g] + part[1][g] + part[2][g] + part[3][g];
        float bb = (g < 8) ? bbeta[g] : (g < 16) ? big[g - 8] : bog[g - 16];
        s += bb;
        s = 1.0f / (1.0f + expf(-s));
        int hh = (g < 8) ? g : (g < 16) ? g - 8 : g - 16;
        float* dst = (g < 8) ? fT : (g < 16) ? gT : oT;
        dst[((size_t)(b * NHEAD + hh)) * LQ + l] = s;
    }
}

// ---------------------------------------------------------------------------
// Merged QKV GEMM: one dispatch, blockIdx.y selects {Wq,Wk,Wv} and {qb,kb,vb}.
// ---------------------------------------------------------------------------
__global__ __launch_bounds__(256) void gemm_qkv(const __hip_bfloat16* __restrict__ A,
                                                const unsigned short* __restrict__ Wqc,
                                                const unsigned short* __restrict__ Wkc,
                                                const unsigned short* __restrict__ Wvc,
                                                unsigned short* __restrict__ qb,
                                                unsigned short* __restrict__ kb,
                                                unsigned short* __restrict__ vb) {
    __shared__ unsigned short As[128 * 32];
    __shared__ unsigned short Bs[128 * 32];
    const int sel = blockIdx.y >> 3;
    const __hip_bfloat16* W = (const __hip_bfloat16*)(sel == 0 ? Wqc : sel == 1 ? Wkc : Wvc);
    unsigned short* C = (sel == 0) ? qb : (sel == 1) ? kb : vb;
    const int tid = threadIdx.x;
    const int lane = tid & 63, wave = tid >> 6;
    const int m0 = blockIdx.x * 128, n0 = (blockIdx.y & 7) * 128;
    const int wm = (wave & 1) * 64, wn = (wave >> 1) * 64;
    const int lm = lane & 15, lq = lane >> 4;
    f32x4 acc[4][4] = {};
    const int c0 = tid, c1 = tid + 256;
    const int r0 = c0 >> 2, o0 = (c0 & 3) * 8;
    const int r1 = c1 >> 2, o1 = (c1 & 3) * 8;
    for (int k0 = 0; k0 < HID; k0 += 32) {
        __builtin_amdgcn_global_load_lds(
            (const __attribute__((address_space(1))) void*)(A + (size_t)(m0 + r0) * HID + k0 + o0),
            (__attribute__((address_space(3))) void*)(As + c0 * 8), 16, 0, 0);
        __builtin_amdgcn_global_load_lds(
            (const __attribute__((address_space(1))) void*)(A + (size_t)(m0 + r1) * HID + k0 + o1),
            (__attribute__((address_space(3))) void*)(As + c1 * 8), 16, 0, 0);
        __builtin_amdgcn_global_load_lds(
            (const __attribute__((address_space(1))) void*)(W + (size_t)(n0 + r0) * HID + k0 + o0),
            (__attribute__((address_space(3))) void*)(Bs + c0 * 8), 16, 0, 0);
        __builtin_amdgcn_global_load_lds(
            (const __attribute__((address_space(1))) void*)(W + (size_t)(n0 + r1) * HID + k0 + o1),
            (__attribute__((address_space(3))) void*)(Bs + c1 * 8), 16, 0, 0);
        __syncthreads();
        bf16x8 af[4], bfr[4];
#pragma unroll
        for (int i = 0; i < 4; ++i)
            af[i] = *(const bf16x8*)(const void*)(As + (wm + i * 16 + lm) * 32 + lq * 8);
#pragma unroll
        for (int j = 0; j < 4; ++j)
            bfr[j] = *(const bf16x8*)(const void*)(Bs + (wn + j * 16 + lm) * 32 + lq * 8);
#pragma unroll
        for (int i = 0; i < 4; ++i)
#pragma unroll
            for (int j = 0; j < 4; ++j)
                acc[i][j] = __builtin_amdgcn_mfma_f32_16x16x32_bf16(af[i], bfr[j], acc[i][j], 0, 0, 0);
        __syncthreads();
    }
#pragma unroll
    for (int i = 0; i < 4; ++i)
#pragma unroll
        for (int j = 0; j < 4; ++j) {
            int col = n0 + wn + j * 16 + lm;
#pragma unroll
            for (int r = 0; r < 4; ++r) {
                int rowg = m0 + wm + i * 16 + lq * 4 + r;
                C[(size_t)rowg * HID + col] = f2us(acc[i][j][r]);
            }
        }
}

// ---------------------------------------------------------------------------
// Final GEMM (m97): C = A W^T + bias; C f32 when (*flagp), else bf16.
// ---------------------------------------------------------------------------
__global__ __launch_bounds__(256) void gemm_bt(const __hip_bfloat16* __restrict__ A,
                                               const __hip_bfloat16* __restrict__ W,
                                               const float* __restrict__ bias,
                                               void* __restrict__ C,
                                               const int* __restrict__ flagp) {
    __shared__ unsigned short As[128 * 32];
    __shared__ unsigned short Bs[128 * 32];
    const bool f32out = (*flagp != 0);
    const int tid = threadIdx.x;
    const int lane = tid & 63, wave = tid >> 6;
    const int m0 = blockIdx.x * 128, n0 = blockIdx.y * 128;
    const int wm = (wave & 1) * 64, wn = (wave >> 1) * 64;
    const int lm = lane & 15, lq = lane >> 4;
    f32x4 acc[4][4] = {};
    const int c0 = tid, c1 = tid + 256;
    const int r0 = c0 >> 2, o0 = (c0 & 3) * 8;
    const int r1 = c1 >> 2, o1 = (c1 & 3) * 8;
    for (int k0 = 0; k0 < HID; k0 += 32) {
        __builtin_amdgcn_global_load_lds(
            (const __attribute__((address_space(1))) void*)(A + (size_t)(m0 + r0) * HID + k0 + o0),
            (__attribute__((address_space(3))) void*)(As + c0 * 8), 16, 0, 0);
        __builtin_amdgcn_global_load_lds(
            (const __attribute__((address_space(1))) void*)(A + (size_t)(m0 + r1) * HID + k0 + o1),
            (__attribute__((address_space(3))) void*)(As + c1 * 8), 16, 0, 0);
        __builtin_amdgcn_global_load_lds(
            (const __attribute__((address_space(1))) void*)(W + (size_t)(n0 + r0) * HID + k0 + o0),
            (__attribute__((address_space(3))) void*)(Bs + c0 * 8), 16, 0, 0);
        __builtin_amdgcn_global_load_lds(
            (const __attribute__((address_space(1))) void*)(W + (size_t)(n0 + r1) * HID + k0 + o1),
            (__attribute__((address_space(3))) void*)(Bs + c1 * 8), 16, 0, 0);
        __syncthreads();
        bf16x8 af[4], bfr[4];
#pragma unroll
        for (int i = 0; i < 4; ++i)
            af[i] = *(const bf16x8*)(const void*)(As + (wm + i * 16 + lm) * 32 + lq * 8);
#pragma unroll
        for (int j = 0; j < 4; ++j)
            bfr[j] = *(const bf16x8*)(const void*)(Bs + (wn + j * 16 + lm) * 32 + lq * 8);
#pragma unroll
        for (int i = 0; i < 4; ++i)
#pragma unroll
            for (int j = 0; j < 4; ++j)
                acc[i][j] = __builtin_amdgcn_mfma_f32_16x16x32_bf16(af[i], bfr[j], acc[i][j], 0, 0, 0);
        __syncthreads();
    }
#pragma unroll
    for (int i = 0; i < 4; ++i)
#pragma unroll
        for (int j = 0; j < 4; ++j) {
            int col = n0 + wn + j * 16 + lm;
            float bv = bias[col];
#pragma unroll
            for (int r = 0; r < 4; ++r) {
                int rowg = m0 + wm + i * 16 + lq * 4 + r;
                size_t idx = (size_t)rowg * HID + col;
                float val = acc[i][j][r] + bv;
                if (f32out) ((float*)C)[idx] = val;
                else ((__hip_bfloat16*)C)[idx] = __float2bfloat16(val);
            }
        }
}

// ---------------------------------------------------------------------------
// INTRA kernel + prep. Q is never staged to LDS: each lane builds its MFMA
// A-fragment of rope(q) in registers (pair i/i+64 lives in the same thread)
// and writes scaled qb back from the same registers. LDS = Kr+Vt+Sp ~46 KB
// -> 3 blocks/CU (was 2).
// ---------------------------------------------------------------------------
__global__ __launch_bounds__(256) void intra_kernel(
    unsigned short* __restrict__ qg, const unsigned short* __restrict__ kg,
    const unsigned short* __restrict__ vg,
    const float* __restrict__ fT, const float* __restrict__ gT, const float* __restrict__ oT,
    const float* __restrict__ cosT, const float* __restrict__ sinT,
    __hip_bfloat16* __restrict__ yb,
    unsigned short* __restrict__ ktg, float* __restrict__ cdecG) {
    const int chunk = blockIdx.x;        // 0..63
    const int bh = blockIdx.y;           // 0..31
    const int b = bh >> 3, hh = bh & 7;
    const int t0 = chunk * CCH;
    const int tid = threadIdx.x;
    const int lane = tid & 63, wave = tid >> 6;
    const int lm = lane & 15, lq = lane >> 4;
    __shared__ unsigned short Kr[64 * 136];
    __shared__ unsigned short Vt[128 * 72];
    __shared__ unsigned short Sp[64 * 72];
    __shared__ float Lp[64], aS[64], osh[64], w2s[64], qscs[64];

    // phase 0: gates + decay prefix (wave 0)
    if (tid < 64) {
        float f = fT[(size_t)bh * LQ + t0 + tid];
        float g = gT[(size_t)bh * LQ + t0 + tid];
        osh[tid] = oT[(size_t)bh * LQ + t0 + tid];
        float lf = __logf(f);
#pragma unroll
        for (int off = 1; off < 64; off <<= 1) {
            float v = __shfl_up(lf, off);
            if (lane >= off) lf += v;
        }
        float tot = __shfl(lf, 63);
        Lp[tid] = lf;
        aS[tid] = g * 0.08838834764831845f;  // g / sqrt(128)
        w2s[tid] = __expf(tot - lf) * (g * 0.08838834764831845f);
        qscs[tid] = __expf(lf);
        if (tid == 63) cdecG[bh * NCH + chunk] = __expf(lf);
    }
    __syncthreads();  // B0

    // phase 1a: Q fragments in registers + scaled write-back.
    // Lane owns row (16*wave+lm), k-cols ks*32+lq*8+[0,8) for ks=0..3.
    bf16x8 af[4];
    {
        const int jr = 16 * wave + lm;
        const int gt = t0 + jr;
        const size_t qbase = ((size_t)(b * LQ + gt)) * HID + hh * DHEAD;
        uint4 qraw[4];
#pragma unroll
        for (int ks = 0; ks < 4; ++ks)
            qraw[ks] = *(const uint4*)(qg + qbase + ks * 32 + lq * 8);
        const unsigned short* q0 = (const unsigned short*)&qraw[0];
        const unsigned short* q1 = (const unsigned short*)&qraw[1];
        const unsigned short* q2 = (const unsigned short*)&qraw[2];
        const unsigned short* q3 = (const unsigned short*)&qraw[3];
        const float sc = qscs[jr];
        __align__(16) unsigned short fr[4][8];
        __align__(16) unsigned short qo[4][8];
#pragma unroll
        for (int u = 0; u < 8; ++u) {
            int i = lq * 8 + u;          // pair (i, i+64) for ks 0<->2
            int i2 = 32 + lq * 8 + u;    // pair for ks 1<->3
            float c0 = cosT[gt * 64 + i], s0 = sinT[gt * 64 + i];
            float c1 = cosT[gt * 64 + i2], s1 = sinT[gt * 64 + i2];
            float a = bf2f(q0[u]), bq = bf2f(q2[u]);
            float rc = a * c0 - bq * s0, rs = a * s0 + bq * c0;
            fr[0][u] = f2us(rc); fr[2][u] = f2us(rs);
            qo[0][u] = f2us(rc * sc); qo[2][u] = f2us(rs * sc);
            float a1 = bf2f(q1[u]), bq1 = bf2f(q3[u]);
            float rc1 = a1 * c1 - bq1 * s1, rs1 = a1 * s1 + bq1 * c1;
            fr[1][u] = f2us(rc1); fr[3][u] = f2us(rs1);
            qo[1][u] = f2us(rc1 * sc); qo[3][u] = f2us(rs1 * sc);
        }
#pragma unroll
        for (int ks = 0; ks < 4; ++ks) {
            af[ks] = *(const bf16x8*)fr[ks];
            *(uint4*)(qg + qbase + ks * 32 + lq * 8) = *(const uint4*)qo[ks];
        }
    }
    // phase 1b: rope-stage K into LDS
#pragma unroll
    for (int r = 0; r < 16; ++r) {
        int pid = r * 256 + tid;
        int t = pid >> 6, i = pid & 63;
        int gt = t0 + t;
        size_t gidx = ((size_t)(b * LQ + gt)) * HID + hh * DHEAD + i;
        float c = cosT[gt * 64 + i], s = sinT[gt * 64 + i];
        float k1 = bf2f(kg[gidx]), k2 = bf2f(kg[gidx + 64]);
        Kr[t * 136 + i] = f2us(k1 * c - k2 * s);
        Kr[t * 136 + i + 64] = f2us(k1 * s + k2 * c);
    }
    // stage V transposed: Vt[e][s]
#pragma unroll
    for (int r = 0; r < 32; ++r) {
        int lin = r * 256 + tid;
        int sI = lin >> 7, e = lin & 127;
        float val = bf2f(vg[((size_t)(b * LQ + t0 + sI)) * HID + hh * DHEAD + e]);
        Vt[e * 72 + sI] = f2us(val);
    }
    __syncthreads();  // B1

    // S = Q K^T (64x64, K=128); wave j-strip [16*wave,+16), Q from registers
    f32x4 sacc[4] = {};
#pragma unroll
    for (int ks = 0; ks < 4; ++ks) {
#pragma unroll
        for (int nt = 0; nt < 4; ++nt) {
            bf16x8 bf = *(const bf16x8*)(const void*)(Kr + (nt * 16 + lm) * 136 + ks * 32 + lq * 8);
            sacc[nt] = __builtin_amdgcn_mfma_f32_16x16x32_bf16(af[ks], bf, sacc[nt], 0, 0, 0);
        }
    }
    // mask + decay/gate scale, store S' bf16 [j][s]
#pragma unroll
    for (int nt = 0; nt < 4; ++nt) {
#pragma unroll
        for (int r = 0; r < 4; ++r) {
            int j = 16 * wave + lq * 4 + r;
            int s = nt * 16 + lm;
            float v = 0.0f;
            if (j >= s) v = sacc[nt][r] * __expf(Lp[j] - Lp[s]) * aS[s];
            Sp[j * 72 + s] = f2us(v);
        }
    }
    // PREP: KtG[ks][d][32] = w2_s * Kr[s][d]
    {
        unsigned short* krec = ktg + ((size_t)(bh * NCH + chunk)) * 8192;
#pragma unroll
        for (int r = 0; r < 2; ++r) {
            int lin16 = r * 256 + tid;
            int ks = lin16 >> 8;
            int d = (lin16 & 255) >> 1;
            int cc0 = (lin16 & 1) * 16;
            __align__(16) unsigned short out[16];
#pragma unroll
            for (int u = 0; u < 16; ++u) {
                int s = ks * 32 + cc0 + u;
                out[u] = f2us(w2s[s] * bf2f(Kr[s * 136 + d]));
            }
            uint4* dst = (uint4*)(krec + (size_t)lin16 * 16);
            dst[0] = *(const uint4*)(out);
            dst[1] = *(const uint4*)(out + 8);
        }
    }
    __syncthreads();  // B2

    // Y_intra = S' V  (64x128, K=64)
    f32x4 ya[8] = {};
#pragma unroll
    for (int ks = 0; ks < 2; ++ks) {
        bf16x8 afs = *(const bf16x8*)(const void*)(Sp + (16 * wave + lm) * 72 + ks * 32 + lq * 8);
#pragma unroll
        for (int nt = 0; nt < 8; ++nt) {
            bf16x8 bf = *(const bf16x8*)(const void*)(Vt + (nt * 16 + lm) * 72 + ks * 32 + lq * 8);
            ya[nt] = __builtin_amdgcn_mfma_f32_16x16x32_bf16(afs, bf, ya[nt], 0, 0, 0);
        }
    }
#pragma unroll
    for (int nt = 0; nt < 8; ++nt) {
#pragma unroll
        for (int r = 0; r < 4; ++r) {
            int j = 16 * wave + lq * 4 + r;
            int e = nt * 16 + lm;
            size_t row = (size_t)(b * LQ + t0 + j);
            yb[row * HID + hh * DHEAD + e] = __float2bfloat16(osh[j] * ya[nt][r]);
        }
    }
}

// ---------------------------------------------------------------------------
// INTER kernel: ONE barrier per chunk. State M double-buffered in LDS (read
// M[c&1], write M[(c+1)&1]) so no second barrier is needed; Q/K DMA for c+1
// issued AFTER the top barrier so it stays in flight through chunk c's
// compute and is drained by the NEXT barrier (true prefetch overlap).
// yb RMW values prefetched right after the barrier to hide their latency.
// ---------------------------------------------------------------------------
__global__ __launch_bounds__(256) void inter_kernel(
    const unsigned short* __restrict__ qs,   // exp(Lp_j)*rope(q), [row][128]
    const unsigned short* __restrict__ ktg,  // [bh][chunk][ks][d][32]
    const unsigned short* __restrict__ vg,
    const float* __restrict__ oT, const float* __restrict__ cdecG,
    unsigned short* __restrict__ yb) {
    const int bh = blockIdx.x;       // 0..31
    const int esplit = blockIdx.y;   // 0..7
    const int e0 = esplit * 16;
    const int b = bh >> 3, hh = bh & 7;
    const int tid = threadIdx.x;
    const int lane = tid & 63, wave = tid >> 6;
    const int lm = lane & 15, lq = lane >> 4;
    __shared__ __align__(16) unsigned short Qsl[2][8192];  // [ks(4)][j(64)][32]
    __shared__ __align__(16) unsigned short Ktl[2][8192];  // [ks(2)][d(128)][32]
    __shared__ __align__(16) unsigned short Vtl[2][1024];  // [ks(2)][e(16)][32]
    __shared__ __align__(16) float Ml[2][16 * 132];        // M^T [e][d], stride 132

    for (int i = tid; i < 16 * 132; i += 256) Ml[0][i] = 0.0f;

    const int jrow = tid >> 2;
    const int qcol = (tid & 3) * 8;
    // prologue: DMA chunk 0 into buf 0, VALU-stage V0
    {
        const unsigned short* qrow =
            qs + ((size_t)(b * LQ + jrow)) * HID + hh * DHEAD + qcol;
#pragma unroll
        for (int ks = 0; ks < 4; ++ks)
            __builtin_amdgcn_global_load_lds(
                (const __attribute__((address_space(1))) void*)(qrow + ks * 32),
                (__attribute__((address_space(3))) void*)(&Qsl[0][ks * 2048 + tid * 8]),
                16, 0, 0);
        const unsigned short* kbase = ktg + ((size_t)(bh * NCH)) * 8192 + tid * 8;
#pragma unroll
        for (int i = 0; i < 4; ++i)
            __builtin_amdgcn_global_load_lds(
                (const __attribute__((address_space(1))) void*)(kbase + i * 2048),
                (__attribute__((address_space(3))) void*)(&Ktl[0][i * 2048 + tid * 8]),
                16, 0, 0);
#pragma unroll
        for (int r = 0; r < 4; ++r) {
            int lin = r * 256 + tid;
            int s = lin >> 4, e = lin & 15;
            float val = bf2f(vg[((size_t)(b * LQ + s)) * HID + hh * DHEAD + e0 + e]);
            Vtl[0][(s >> 5) * 512 + e * 32 + (s & 31)] = f2us(val);
        }
    }

    for (int c = 0; c < NCH; ++c) {
        const int cur = c & 1, nxt = cur ^ 1;
        const int t0 = c * CCH;
        __syncthreads();  // drains chunk-c DMA (issued last iter), M[cur] visible
        // issue DMA for c+1 (drained at NEXT barrier -> overlaps this compute)
        if (c + 1 < NCH) {
            const int t0n = t0 + CCH;
            const unsigned short* qrow =
                qs + ((size_t)(b * LQ + t0n + jrow)) * HID + hh * DHEAD + qcol;
#pragma unroll
            for (int ks = 0; ks < 4; ++ks)
                __builtin_amdgcn_global_load_lds(
                    (const __attribute__((address_space(1))) void*)(qrow + ks * 32),
                    (__attribute__((address_space(3))) void*)(&Qsl[nxt][ks * 2048 + tid * 8]),
                    16, 0, 0);
            const unsigned short* kbase = ktg + ((size_t)(bh * NCH + c + 1)) * 8192 + tid * 8;
#pragma unroll
            for (int i = 0; i < 4; ++i)
                __builtin_amdgcn_global_load_lds(
                    (const __attribute__((address_space(1))) void*)(kbase + i * 2048),
                    (__attribute__((address_space(3))) void*)(&Ktl[nxt][i * 2048 + tid * 8]),
                    16, 0, 0);
        }
        // early yb/o prefetch (consumed after MFMAs)
        size_t yidx[4];
        unsigned short prevy[4];
        float osv[4];
#pragma unroll
        for (int r = 0; r < 4; ++r) {
            int j = 16 * wave + lq * 4 + r;
            yidx[r] = ((size_t)(b * LQ + t0 + j)) * HID + hh * DHEAD + e0 + lm;
            prevy[r] = yb[yidx[r]];
            osv[r] = oT[(size_t)bh * LQ + t0 + j];
        }
        const float cd = cdecG[bh * NCH + c];
        // U = K''^T V : wave d-strip [32*wave, +32)
        f32x4 uacc[2] = {};
#pragma unroll
        for (int ks = 0; ks < 2; ++ks) {
            bf16x8 bfv = *(const bf16x8*)(const void*)(&Vtl[cur][ks * 512 + lm * 32 + lq * 8]);
#pragma unroll
            for (int mt = 0; mt < 2; ++mt) {
                bf16x8 af = *(const bf16x8*)(const void*)(
                    &Ktl[cur][ks * 4096 + (32 * wave + 16 * mt + lm) * 32 + lq * 8]);
                uacc[mt] = __builtin_amdgcn_mfma_f32_16x16x32_bf16(af, bfv, uacc[mt], 0, 0, 0);
            }
        }
        // Y = Qs @ M[cur] : wave j-strip [16*wave, +16)
        f32x4 yacc = {};
#pragma unroll
        for (int ks = 0; ks < 4; ++ks) {
            bf16x8 af = *(const bf16x8*)(const void*)(
                &Qsl[cur][ks * 2048 + (16 * wave + lm) * 32 + lq * 8]);
            float4 m0 = *(const float4*)(const void*)(&Ml[cur][lm * 132 + ks * 32 + lq * 8]);
            float4 m1 = *(const float4*)(const void*)(&Ml[cur][lm * 132 + ks * 32 + lq * 8 + 4]);
            __align__(16) unsigned short tmp[8];
            tmp[0] = f2us(m0.x); tmp[1] = f2us(m0.y); tmp[2] = f2us(m0.z); tmp[3] = f2us(m0.w);
            tmp[4] = f2us(m1.x); tmp[5] = f2us(m1.y); tmp[6] = f2us(m1.z); tmp[7] = f2us(m1.w);
            bf16x8 bfm = *(const bf16x8*)tmp;
            yacc = __builtin_amdgcn_mfma_f32_16x16x32_bf16(af, bfm, yacc, 0, 0, 0);
        }
        // yb += o * Y_inter
#pragma unroll
        for (int r = 0; r < 4; ++r)
            yb[yidx[r]] = f2us(bf2f(prevy[r]) + osv[r] * yacc[r]);
        // VALU-stage V for chunk c+1 into nxt buffer
        if (c + 1 < NCH) {
            const int t0n = t0 + CCH;
#pragma unroll
            for (int r = 0; r < 4; ++r) {
                int lin = r * 256 + tid;
                int s = lin >> 4, e = lin & 15;
                float val = bf2f(vg[((size_t)(b * LQ + t0n + s)) * HID + hh * DHEAD + e0 + e]);
                Vtl[nxt][(s >> 5) * 512 + e * 32 + (s & 31)] = f2us(val);
            }
        }
        // M[nxt] = cd * M[cur] + U  (write other buffer -> no barrier needed)
#pragma unroll
        for (int mt = 0; mt < 2; ++mt)
#pragma unroll
            for (int r = 0; r < 4; ++r) {
                int d = 32 * wave + 16 * mt + lq * 4 + r;
                Ml[nxt][lm * 132 + d] = cd * Ml[cur][lm * 132 + d] + uacc[mt][r];
            }
    }
}

// ---------------------------------------------------------------------------
extern "C" void kernel_launch(void* const* d_in, const int* in_sizes, int n_in,
                              void* d_out, int out_size, void* d_ws, size_t ws_size,
                              hipStream_t stream) {
    const void* x      = d_in[0];
    const void* norm_w = d_in[1];
    const void* Wq     = d_in[2];
    const void* Wk     = d_in[3];
    const void* Wv     = d_in[4];
    const void* Wbeta  = d_in[5];
    const void* bbeta  = d_in[6];
    const void* Wig    = d_in[7];
    const void* big    = d_in[8];
    const void* Wog    = d_in[9];
    const void* bog    = d_in[10];
    const void* Wout   = d_in[11];
    const void* bout   = d_in[12];

    char* ws = (char*)d_ws;
    const size_t KB = 1024, MB = 1024 * 1024;
    int*   flag    = (int*)(ws + 0);
    float* bbeta_c = (float*)(ws + 1 * KB);
    float* big_c   = (float*)(ws + 1 * KB + 32);
    float* bog_c   = (float*)(ws + 1 * KB + 64);
    float* bout_c  = (float*)(ws + 4 * KB);
    float* cdecG   = (float*)(ws + 16 * KB);            // 8 KiB
    unsigned short* Wbeta_c = (unsigned short*)(ws + 64 * KB);
    unsigned short* Wig_c   = (unsigned short*)(ws + 96 * KB);
    unsigned short* Wog_c   = (unsigned short*)(ws + 128 * KB);
    float* fT   = (float*)(ws + 1 * MB);
    float* gT   = (float*)(ws + 1 * MB + 512 * KB);
    float* oT   = (float*)(ws + 2 * MB);
    float* cosT = (float*)(ws + 2 * MB + 512 * KB);
    float* sinT = (float*)(ws + 3 * MB + 512 * KB);
    unsigned short* Wq_c   = (unsigned short*)(ws + 5 * MB);
    unsigned short* Wk_c   = (unsigned short*)(ws + 7 * MB);
    unsigned short* Wv_c   = (unsigned short*)(ws + 9 * MB);
    unsigned short* Wout_c = (unsigned short*)(ws + 11 * MB);
    __hip_bfloat16* h  = (__hip_bfloat16*)(ws + 16 * MB);   // 32 MiB; dead after QKV gemm
    unsigned short* ktg = (unsigned short*)(ws + 16 * MB);  // aliases h (32 MiB)
    unsigned short* qb = (unsigned short*)(ws + 48 * MB);
    unsigned short* kb = (unsigned short*)(ws + 80 * MB);
    unsigned short* vb = (unsigned short*)(ws + 112 * MB);
    __hip_bfloat16* yb = (__hip_bfloat16*)(ws + 144 * MB);

    detect_kernel<<<1, 64, 0, stream>>>(x, flag);
    cvt_w4_kernel<<<dim3(1024, 5), 256, 0, stream>>>(Wq, Wk, Wv, Wout,
                                                     Wq_c, Wk_c, Wv_c, Wout_c,
                                                     cosT, sinT, flag);
    cvt_small_kernel<<<101, 256, 0, stream>>>(Wbeta, Wig, Wog, bbeta, big, bog, bout,
                                              Wbeta_c, Wig_c, Wog_c,
                                              bbeta_c, big_c, bog_c, bout_c, flag);
    rmsnorm_gates_kernel<<<MROWS, 256, 0, stream>>>(
        x, norm_w, h, flag,
        (const __hip_bfloat16*)Wbeta_c, bbeta_c,
        (const __hip_bfloat16*)Wig_c, big_c,
        (const __hip_bfloat16*)Wog_c, bog_c, fT, gT, oT);

    gemm_qkv<<<dim3(MROWS / 128, 24), 256, 0, stream>>>(h, Wq_c, Wk_c, Wv_c, qb, kb, vb);

    intra_kernel<<<dim3(NCH, 32), 256, 0, stream>>>(qb, kb, vb, fT, gT, oT, cosT, sinT,
                                                    (__hip_bfloat16*)yb, ktg, cdecG);
    inter_kernel<<<dim3(32, 8), 256, 0, stream>>>(qb, ktg, vb, oT, cdecG,
                                                  (unsigned short*)yb);

    gemm_bt<<<dim3(MROWS / 128, HID / 128), 256, 0, stream>>>(
        (const __hip_bfloat16*)yb, (const __hip_bfloat16*)Wout_c, bout_c, d_out, flag);
}